// Round 1
// baseline (475.550 us; speedup 1.0000x reference)
//
#include <hip/hip_runtime.h>
#include <hip/hip_fp16.h>
#include <stdint.h>

typedef _Float16 f16;
typedef _Float16 f16x8 __attribute__((ext_vector_type(8)));
typedef _Float16 f16x4v __attribute__((ext_vector_type(4)));
typedef float f32x4 __attribute__((ext_vector_type(4)));

#define MFMA16(a,b,c) __builtin_amdgcn_mfma_f32_16x16x32_f16(a,b,c,0,0,0)

typedef __attribute__((address_space(1))) void gvoid_t;
typedef __attribute__((address_space(3))) void svoid_t;
#define AS1(p) ((gvoid_t*)(uintptr_t)(p))
#define AS3(p) ((svoid_t*)(uint32_t)(uintptr_t)(p))

static constexpr int Bc = 2, Tc = 2048, Dc = 768, Hc = 12;
static constexpr int Mc = Bc * Tc;                      // 4096
static constexpr float SC2 = 0.18033688011112042f;      // (1/8) * log2(e)

// ---------------- f32 -> f16 conversion (all inputs + weights) ----------------
__global__ __launch_bounds__(256) void conv_all(
    const float* __restrict__ q, const float* __restrict__ k, const float* __restrict__ v,
    const float* __restrict__ wq, const float* __restrict__ wk, const float* __restrict__ wv,
    const float* __restrict__ wo,
    f16* __restrict__ qh, f16* __restrict__ kh, f16* __restrict__ vh,
    f16* __restrict__ wqh, f16* __restrict__ wkh, f16* __restrict__ wvh, f16* __restrict__ woh)
{
    const int NI = (Mc * Dc) / 4;   // 786432 float4 per input
    const int NW = (Dc * Dc) / 4;   // 147456 float4 per weight
    int i = blockIdx.x * 256 + threadIdx.x;
    if (i >= 3 * NI + 4 * NW) return;
    const float4* src; f16* dst; int j;
    if (i < 3 * NI) {
        int a = i / NI; j = i - a * NI;
        src = (const float4*)(a == 0 ? q : (a == 1 ? k : v));
        dst = (a == 0 ? qh : (a == 1 ? kh : vh));
    } else {
        int t = i - 3 * NI;
        int a = t / NW; j = t - a * NW;
        src = (const float4*)(a == 0 ? wq : (a == 1 ? wk : (a == 2 ? wv : wo)));
        dst = (a == 0 ? wqh : (a == 1 ? wkh : (a == 2 ? wvh : woh)));
    }
    float4 f = src[j];
    f16x4v o = { (f16)f.x, (f16)f.y, (f16)f.z, (f16)f.w };
    *(f16x4v*)(dst + 4 * j) = o;
}

// ---------------- 128x128 GEMM mainloop: C = A @ W^T over K=768 ----------------
// A:[M][768] f16 row-major, W:[768][768] f16 row-major. 256 threads, 4 waves (2x2).
__device__ __forceinline__ void gemm_tile_mainloop(
    const f16* __restrict__ A, const f16* __restrict__ W,
    int brow, int bcol, f16* As, f16* Bs, f32x4 acc[4][4])
{
    const int tid = threadIdx.x;
    const int w = tid >> 6, lane = tid & 63;
    const int lg = lane & 15, hg = lane >> 4;
    const int wr = w >> 1, wc = w & 1;

    for (int kt = 0; kt < 768 / 32; ++kt) {
        const int k0 = kt * 32;
#pragma unroll
        for (int j = 0; j < 2; ++j) {
            int p = (w * 2 + j) * 1024 + lane * 16;   // byte offset within tile
            int r = p >> 6;                            // row (64B per row of 32 f16)
            int ke = (p & 63) >> 1;                    // k element within row
            __builtin_amdgcn_global_load_lds(AS1(A + (size_t)(brow + r) * 768 + k0 + ke),
                                             AS3((char*)As + (w * 2 + j) * 1024), 16, 0, 0);
            __builtin_amdgcn_global_load_lds(AS1(W + (size_t)(bcol + r) * 768 + k0 + ke),
                                             AS3((char*)Bs + (w * 2 + j) * 1024), 16, 0, 0);
        }
        __syncthreads();
        f16x8 af[4], bf[4];
#pragma unroll
        for (int m = 0; m < 4; ++m)
            af[m] = *(const f16x8*)(As + (wr * 64 + m * 16 + lg) * 32 + hg * 8);
#pragma unroll
        for (int n = 0; n < 4; ++n)
            bf[n] = *(const f16x8*)(Bs + (wc * 64 + n * 16 + lg) * 32 + hg * 8);
#pragma unroll
        for (int m = 0; m < 4; ++m)
#pragma unroll
            for (int n = 0; n < 4; ++n)
                acc[m][n] = MFMA16(af[m], bf[n], acc[m][n]);
        __syncthreads();
    }
}

// ---------------- QKV projections (z: 0=Q, 1=K, 2=V-transposed) ----------------
__global__ __launch_bounds__(256) void qkv_proj(
    const f16* __restrict__ qh, const f16* __restrict__ kh, const f16* __restrict__ vh,
    const f16* __restrict__ wqh, const f16* __restrict__ wkh, const f16* __restrict__ wvh,
    const float* __restrict__ bq, const float* __restrict__ bk, const float* __restrict__ bv,
    f16* __restrict__ Qp, f16* __restrict__ Kp, f16* __restrict__ Vt)
{
    __shared__ f16 As[128 * 32], Bs[128 * 32];
    const int z = blockIdx.z;
    const f16* A = (z == 0) ? qh : (z == 1) ? kh : vh;
    const f16* W = (z == 0) ? wqh : (z == 1) ? wkh : wvh;
    const float* bias = (z == 0) ? bq : (z == 1) ? bk : bv;
    const int brow = blockIdx.y * 128, bcol = blockIdx.x * 128;

    f32x4 acc[4][4];
    const f32x4 z4 = { 0.f, 0.f, 0.f, 0.f };
#pragma unroll
    for (int m = 0; m < 4; ++m)
#pragma unroll
        for (int n = 0; n < 4; ++n) acc[m][n] = z4;

    gemm_tile_mainloop(A, W, brow, bcol, As, Bs, acc);

    const int tid = threadIdx.x, w = tid >> 6, lane = tid & 63;
    const int lg = lane & 15, hg = lane >> 4, wr = w >> 1, wc = w & 1;
#pragma unroll
    for (int n = 0; n < 4; ++n) {
        const int c = bcol + wc * 64 + n * 16 + lg;
        const float bval = bias[c];
#pragma unroll
        for (int m = 0; m < 4; ++m) {
            const int r0 = brow + wr * 64 + m * 16 + hg * 4;
#pragma unroll
            for (int r = 0; r < 4; ++r) {
                const float val = acc[m][n][r] + bval;
                const int row = r0 + r;
                if (z == 0) {
                    Qp[(size_t)row * 768 + c] = (f16)val;
                } else if (z == 1) {
                    Kp[(size_t)row * 768 + c] = (f16)val;
                } else {
                    const int bb = row >> 11, t = row & 2047;
                    const int h = c >> 6, d = c & 63;
                    Vt[(((size_t)(bb * 12 + h)) * 64 + d) * 2048 + t] = (f16)val;
                }
            }
        }
    }
}

// ---------------- output projection: out = ctx @ Wo^T + bo (f32 out) ----------------
__global__ __launch_bounds__(256) void out_proj(
    const f16* __restrict__ ctx, const f16* __restrict__ woh,
    const float* __restrict__ bo, float* __restrict__ out)
{
    __shared__ f16 As[128 * 32], Bs[128 * 32];
    const int brow = blockIdx.y * 128, bcol = blockIdx.x * 128;
    f32x4 acc[4][4];
    const f32x4 z4 = { 0.f, 0.f, 0.f, 0.f };
#pragma unroll
    for (int m = 0; m < 4; ++m)
#pragma unroll
        for (int n = 0; n < 4; ++n) acc[m][n] = z4;

    gemm_tile_mainloop(ctx, woh, brow, bcol, As, Bs, acc);

    const int tid = threadIdx.x, w = tid >> 6, lane = tid & 63;
    const int lg = lane & 15, hg = lane >> 4, wr = w >> 1, wc = w & 1;
#pragma unroll
    for (int n = 0; n < 4; ++n) {
        const int c = bcol + wc * 64 + n * 16 + lg;
        const float bval = bo[c];
#pragma unroll
        for (int m = 0; m < 4; ++m) {
            const int r0 = brow + wr * 64 + m * 16 + hg * 4;
#pragma unroll
            for (int r = 0; r < 4; ++r)
                out[(size_t)(r0 + r) * 768 + c] = acc[m][n][r] + bval;
        }
    }
}

// ---------------- pass 1: softmax row stats (exp2 domain) ----------------
__global__ __launch_bounds__(256) void attn_stats(
    const f16* __restrict__ Qp, const f16* __restrict__ Kp,
    float* __restrict__ m_arr, float* __restrict__ l_arr)
{
    const int qt = blockIdx.x, h = blockIdx.y, b = blockIdx.z;
    const int tid = threadIdx.x, w = tid >> 6, lane = tid & 63;
    const int lg = lane & 15, hg = lane >> 4;

    const size_t qrow0 = (size_t)b * 2048 + qt * 64 + w * 16;
    const f16* qbase = Qp + (qrow0 + lg) * 768 + h * 64 + hg * 8;
    const f16x8 aq0 = *(const f16x8*)(qbase);
    const f16x8 aq1 = *(const f16x8*)(qbase + 32);

    float m_run[4], l_run[4];
#pragma unroll
    for (int r = 0; r < 4; ++r) { m_run[r] = -1e30f; l_run[r] = 0.f; }

    const f32x4 z4 = { 0.f, 0.f, 0.f, 0.f };
    for (int kt = 0; kt < 32; ++kt) {
        const size_t krow0 = (size_t)b * 2048 + kt * 64;
        f32x4 sa[4];
#pragma unroll
        for (int n = 0; n < 4; ++n) sa[n] = z4;
#pragma unroll
        for (int n = 0; n < 4; ++n) {
            const f16* kb = Kp + (krow0 + n * 16 + lg) * 768 + h * 64 + hg * 8;
            sa[n] = MFMA16(aq0, *(const f16x8*)kb, sa[n]);
            sa[n] = MFMA16(aq1, *(const f16x8*)(kb + 32), sa[n]);
        }
#pragma unroll
        for (int r = 0; r < 4; ++r) {
            float tm = fmaxf(fmaxf(sa[0][r], sa[1][r]), fmaxf(sa[2][r], sa[3][r]));
            tm = fmaxf(tm, __shfl_xor(tm, 1));
            tm = fmaxf(tm, __shfl_xor(tm, 2));
            tm = fmaxf(tm, __shfl_xor(tm, 4));
            tm = fmaxf(tm, __shfl_xor(tm, 8));
            tm *= SC2;
            const float mn = fmaxf(m_run[r], tm);
            float s = exp2f(sa[0][r] * SC2 - mn) + exp2f(sa[1][r] * SC2 - mn)
                    + exp2f(sa[2][r] * SC2 - mn) + exp2f(sa[3][r] * SC2 - mn);
            s += __shfl_xor(s, 1);
            s += __shfl_xor(s, 2);
            s += __shfl_xor(s, 4);
            s += __shfl_xor(s, 8);
            l_run[r] = l_run[r] * exp2f(m_run[r] - mn) + s;
            m_run[r] = mn;
        }
    }
    if (lg == 0) {
        const size_t sbase = ((size_t)(b * 12 + h)) * 2048 + qt * 64 + w * 16 + hg * 4;
#pragma unroll
        for (int r = 0; r < 4; ++r) { m_arr[sbase + r] = m_run[r]; l_arr[sbase + r] = l_run[r]; }
    }
}

// ---------------- pass 2a: attn mean over heads ----------------
__global__ __launch_bounds__(256) void attn_mean(
    const f16* __restrict__ Qp, const f16* __restrict__ Kp,
    const float* __restrict__ m_arr, const float* __restrict__ l_arr,
    float* __restrict__ om)
{
    const int kt = blockIdx.x, qt = blockIdx.y, b = blockIdx.z;
    const int tid = threadIdx.x, w = tid >> 6, lane = tid & 63;
    const int lg = lane & 15, hg = lane >> 4;
    const size_t qrow0 = (size_t)b * 2048 + qt * 64 + w * 16;
    const size_t krow0 = (size_t)b * 2048 + kt * 64;

    float macc[4][4];
#pragma unroll
    for (int n = 0; n < 4; ++n)
#pragma unroll
        for (int r = 0; r < 4; ++r) macc[n][r] = 0.f;

    const f32x4 z4 = { 0.f, 0.f, 0.f, 0.f };
    for (int h = 0; h < 12; ++h) {
        const f16* qbase = Qp + (qrow0 + lg) * 768 + h * 64 + hg * 8;
        const f16x8 aq0 = *(const f16x8*)(qbase);
        const f16x8 aq1 = *(const f16x8*)(qbase + 32);
        f32x4 sa[4];
#pragma unroll
        for (int n = 0; n < 4; ++n) sa[n] = z4;
#pragma unroll
        for (int n = 0; n < 4; ++n) {
            const f16* kb = Kp + (krow0 + n * 16 + lg) * 768 + h * 64 + hg * 8;
            sa[n] = MFMA16(aq0, *(const f16x8*)kb, sa[n]);
            sa[n] = MFMA16(aq1, *(const f16x8*)(kb + 32), sa[n]);
        }
        const size_t sbase = ((size_t)(b * 12 + h)) * 2048 + qt * 64 + w * 16 + hg * 4;
        float mv[4], iv[4];
#pragma unroll
        for (int r = 0; r < 4; ++r) { mv[r] = m_arr[sbase + r]; iv[r] = 1.f / l_arr[sbase + r]; }
#pragma unroll
        for (int n = 0; n < 4; ++n)
#pragma unroll
            for (int r = 0; r < 4; ++r)
                macc[n][r] += exp2f(sa[n][r] * SC2 - mv[r]) * iv[r];
    }
#pragma unroll
    for (int n = 0; n < 4; ++n)
#pragma unroll
        for (int r = 0; r < 4; ++r) {
            const size_t row = qrow0 + hg * 4 + r;   // already includes b*2048
            const size_t col = (size_t)kt * 64 + n * 16 + lg;
            om[row * 2048 + col] = macc[n][r] * (1.0f / 12.0f);
        }
}

// ---------------- pass 2b: attention output (P @ V) ----------------
__global__ __launch_bounds__(256) void attn_out(
    const f16* __restrict__ Qp, const f16* __restrict__ Kp, const f16* __restrict__ Vt,
    const float* __restrict__ m_arr, const float* __restrict__ l_arr,
    f16* __restrict__ ctx)
{
    __shared__ f16 P[4][16][72];   // per-wave P tile, padded
    const int qt = blockIdx.x, h = blockIdx.y, b = blockIdx.z;
    const int tid = threadIdx.x, w = tid >> 6, lane = tid & 63;
    const int lg = lane & 15, hg = lane >> 4;

    const size_t qrow0 = (size_t)b * 2048 + qt * 64 + w * 16;
    const f16* qbase = Qp + (qrow0 + lg) * 768 + h * 64 + hg * 8;
    const f16x8 aq0 = *(const f16x8*)(qbase);
    const f16x8 aq1 = *(const f16x8*)(qbase + 32);

    const size_t sbase = ((size_t)(b * 12 + h)) * 2048 + qt * 64 + w * 16 + hg * 4;
    float mv[4], iv[4];
#pragma unroll
    for (int r = 0; r < 4; ++r) { mv[r] = m_arr[sbase + r]; iv[r] = 1.f / l_arr[sbase + r]; }

    const f32x4 z4 = { 0.f, 0.f, 0.f, 0.f };
    f32x4 oacc[4];
#pragma unroll
    for (int n = 0; n < 4; ++n) oacc[n] = z4;

    const size_t vbase = ((size_t)(b * 12 + h)) * 64 * 2048;

    for (int kt = 0; kt < 32; ++kt) {
        const size_t krow0 = (size_t)b * 2048 + kt * 64;
        f32x4 sa[4];
#pragma unroll
        for (int n = 0; n < 4; ++n) sa[n] = z4;
#pragma unroll
        for (int n = 0; n < 4; ++n) {
            const f16* kb = Kp + (krow0 + n * 16 + lg) * 768 + h * 64 + hg * 8;
            sa[n] = MFMA16(aq0, *(const f16x8*)kb, sa[n]);
            sa[n] = MFMA16(aq1, *(const f16x8*)(kb + 32), sa[n]);
        }
#pragma unroll
        for (int n = 0; n < 4; ++n)
#pragma unroll
            for (int r = 0; r < 4; ++r) {
                const float p = exp2f(sa[n][r] * SC2 - mv[r]) * iv[r];
                P[w][hg * 4 + r][n * 16 + lg] = (f16)p;
            }
        const f16x8 pa0 = *(const f16x8*)&P[w][lg][hg * 8];
        const f16x8 pa1 = *(const f16x8*)&P[w][lg][32 + hg * 8];
#pragma unroll
        for (int n = 0; n < 4; ++n) {
            const f16* vb = Vt + vbase + (size_t)(n * 16 + lg) * 2048 + kt * 64 + hg * 8;
            oacc[n] = MFMA16(pa0, *(const f16x8*)vb, oacc[n]);
            oacc[n] = MFMA16(pa1, *(const f16x8*)(vb + 32), oacc[n]);
        }
    }
#pragma unroll
    for (int n = 0; n < 4; ++n)
#pragma unroll
        for (int r = 0; r < 4; ++r)
            ctx[(qrow0 + hg * 4 + r) * 768 + h * 64 + n * 16 + lg] = (f16)oacc[n][r];
}

// ---------------- launch ----------------
extern "C" void kernel_launch(void* const* d_in, const int* in_sizes, int n_in,
                              void* d_out, int out_size, void* d_ws, size_t ws_size,
                              hipStream_t stream) {
    const float* q  = (const float*)d_in[0];
    const float* k  = (const float*)d_in[1];
    const float* v  = (const float*)d_in[2];
    const float* Wq = (const float*)d_in[3];
    const float* bq = (const float*)d_in[4];
    const float* Wk = (const float*)d_in[5];
    const float* bk = (const float*)d_in[6];
    const float* Wv = (const float*)d_in[7];
    const float* bv = (const float*)d_in[8];
    const float* Wo = (const float*)d_in[9];
    const float* bo = (const float*)d_in[10];
    float* out = (float*)d_out;

    char* ws = (char*)d_ws;
    const size_t SZ_IN = (size_t)Mc * Dc * 2;   // 6291456 bytes
    const size_t SZ_W  = (size_t)Dc * Dc * 2;   // 1179648 bytes
    f16* qh  = (f16*)(ws);
    f16* kh  = (f16*)(ws + SZ_IN);
    f16* vh  = (f16*)(ws + 2 * SZ_IN);
    f16* wqh = (f16*)(ws + 3 * SZ_IN);
    f16* wkh = (f16*)(ws + 3 * SZ_IN + SZ_W);
    f16* wvh = (f16*)(ws + 3 * SZ_IN + 2 * SZ_W);
    f16* woh = (f16*)(ws + 3 * SZ_IN + 3 * SZ_W);
    f16* Qp  = (f16*)(ws + 3 * SZ_IN + 4 * SZ_W);
    f16* Kp  = (f16*)(ws + 4 * SZ_IN + 4 * SZ_W);
    f16* Vt  = (f16*)(ws + 5 * SZ_IN + 4 * SZ_W);
    // dead-buffer reuse: ctx lives in qh's slot, softmax stats in kh's slot
    f16* ctx = qh;
    float* m_arr = (float*)kh;
    float* l_arr = m_arr + (size_t)Bc * Hc * Tc;

    conv_all<<<dim3(11520), dim3(256), 0, stream>>>(q, k, v, Wq, Wk, Wv, Wo,
                                                    qh, kh, vh, wqh, wkh, wvh, woh);
    qkv_proj<<<dim3(6, 32, 3), dim3(256), 0, stream>>>(qh, kh, vh, wqh, wkh, wvh,
                                                       bq, bk, bv, Qp, Kp, Vt);
    attn_stats<<<dim3(32, 12, 2), dim3(256), 0, stream>>>(Qp, Kp, m_arr, l_arr);
    attn_mean<<<dim3(32, 32, 2), dim3(256), 0, stream>>>(Qp, Kp, m_arr, l_arr,
                                                         out + (size_t)Mc * Dc);
    attn_out<<<dim3(32, 12, 2), dim3(256), 0, stream>>>(Qp, Kp, Vt, m_arr, l_arr, ctx);
    out_proj<<<dim3(6, 32, 1), dim3(256), 0, stream>>>(ctx, woh, bo, out);
}

// Round 3
// 361.309 us; speedup vs baseline: 1.3162x; 1.3162x over previous
//
#include <hip/hip_runtime.h>
#include <hip/hip_fp16.h>
#include <stdint.h>

typedef _Float16 f16;
typedef _Float16 f16x8 __attribute__((ext_vector_type(8)));
typedef _Float16 f16x4v __attribute__((ext_vector_type(4)));
typedef __fp16 h16x2 __attribute__((ext_vector_type(2)));   // cvt_pkrtz return type
typedef float f32x4 __attribute__((ext_vector_type(4)));

#define MFMA16(a,b,c) __builtin_amdgcn_mfma_f32_16x16x32_f16(a,b,c,0,0,0)
#define CVTPK(a,b) __builtin_amdgcn_cvt_pkrtz(a,b)

typedef __attribute__((address_space(1))) void gvoid_t;
typedef __attribute__((address_space(3))) void svoid_t;
#define AS1(p) ((gvoid_t*)(uintptr_t)(p))
#define AS3(p) ((svoid_t*)(uint32_t)(uintptr_t)(p))

static constexpr int Bc = 2, Tc = 2048, Dc = 768, Hc = 12;
static constexpr int Mc = Bc * Tc;                      // 4096
static constexpr float SC2 = 0.18033688011112042f;      // (1/8) * log2(e)

union PA { f16x8 v; h16x2 h[4]; };

// ---------------- f32 -> f16 conversion (all inputs + weights) ----------------
__global__ __launch_bounds__(256) void conv_all(
    const float* __restrict__ q, const float* __restrict__ k, const float* __restrict__ v,
    const float* __restrict__ wq, const float* __restrict__ wk, const float* __restrict__ wv,
    const float* __restrict__ wo,
    f16* __restrict__ qh, f16* __restrict__ kh, f16* __restrict__ vh,
    f16* __restrict__ wqh, f16* __restrict__ wkh, f16* __restrict__ wvh, f16* __restrict__ woh)
{
    const int NI = (Mc * Dc) / 4;
    const int NW = (Dc * Dc) / 4;
    int i = blockIdx.x * 256 + threadIdx.x;
    if (i >= 3 * NI + 4 * NW) return;
    const float4* src; f16* dst; int j;
    if (i < 3 * NI) {
        int a = i / NI; j = i - a * NI;
        src = (const float4*)(a == 0 ? q : (a == 1 ? k : v));
        dst = (a == 0 ? qh : (a == 1 ? kh : vh));
    } else {
        int t = i - 3 * NI;
        int a = t / NW; j = t - a * NW;
        src = (const float4*)(a == 0 ? wq : (a == 1 ? wk : (a == 2 ? wv : wo)));
        dst = (a == 0 ? wqh : (a == 1 ? wkh : (a == 2 ? wvh : woh)));
    }
    float4 f = src[j];
    f16x4v o = { (f16)f.x, (f16)f.y, (f16)f.z, (f16)f.w };
    *(f16x4v*)(dst + 4 * j) = o;
}

// ---------------- 128x128 GEMM mainloop: C = A @ W^T over K=768 ----------------
__device__ __forceinline__ void gemm_tile_mainloop(
    const f16* __restrict__ A, const f16* __restrict__ W,
    int brow, int bcol, f16* As, f16* Bs, f32x4 acc[4][4])
{
    const int tid = threadIdx.x;
    const int w = tid >> 6, lane = tid & 63;
    const int lg = lane & 15, hg = lane >> 4;
    const int wr = w >> 1, wc = w & 1;

    for (int kt = 0; kt < 768 / 32; ++kt) {
        const int k0 = kt * 32;
#pragma unroll
        for (int j = 0; j < 2; ++j) {
            int p = (w * 2 + j) * 1024 + lane * 16;
            int r = p >> 6;
            int ke = (p & 63) >> 1;
            __builtin_amdgcn_global_load_lds(AS1(A + (size_t)(brow + r) * 768 + k0 + ke),
                                             AS3((char*)As + (w * 2 + j) * 1024), 16, 0, 0);
            __builtin_amdgcn_global_load_lds(AS1(W + (size_t)(bcol + r) * 768 + k0 + ke),
                                             AS3((char*)Bs + (w * 2 + j) * 1024), 16, 0, 0);
        }
        __syncthreads();
        f16x8 af[4], bf[4];
#pragma unroll
        for (int m = 0; m < 4; ++m)
            af[m] = *(const f16x8*)(As + (wr * 64 + m * 16 + lg) * 32 + hg * 8);
#pragma unroll
        for (int n = 0; n < 4; ++n)
            bf[n] = *(const f16x8*)(Bs + (wc * 64 + n * 16 + lg) * 32 + hg * 8);
#pragma unroll
        for (int m = 0; m < 4; ++m)
#pragma unroll
            for (int n = 0; n < 4; ++n)
                acc[m][n] = MFMA16(af[m], bf[n], acc[m][n]);
        __syncthreads();
    }
}

// ---------------- QKV projections (z: 0=Q, 1=K, 2=V-transposed+permuted) ----------------
__global__ __launch_bounds__(256) void qkv_proj(
    const f16* __restrict__ qh, const f16* __restrict__ kh, const f16* __restrict__ vh,
    const f16* __restrict__ wqh, const f16* __restrict__ wkh, const f16* __restrict__ wvh,
    const float* __restrict__ bq, const float* __restrict__ bk, const float* __restrict__ bv,
    f16* __restrict__ Qp, f16* __restrict__ Kp, f16* __restrict__ Vt)
{
    __shared__ f16 As[128 * 32], Bs[128 * 32];
    const int z = blockIdx.z;
    const f16* A = (z == 0) ? qh : (z == 1) ? kh : vh;
    const f16* W = (z == 0) ? wqh : (z == 1) ? wkh : wvh;
    const float* bias = (z == 0) ? bq : (z == 1) ? bk : bv;
    const int brow = blockIdx.y * 128, bcol = blockIdx.x * 128;

    f32x4 acc[4][4];
    const f32x4 z4 = { 0.f, 0.f, 0.f, 0.f };
#pragma unroll
    for (int m = 0; m < 4; ++m)
#pragma unroll
        for (int n = 0; n < 4; ++n) acc[m][n] = z4;

    gemm_tile_mainloop(A, W, brow, bcol, As, Bs, acc);

    const int tid = threadIdx.x, w = tid >> 6, lane = tid & 63;
    const int lg = lane & 15, hg = lane >> 4, wr = w >> 1, wc = w & 1;
#pragma unroll
    for (int n = 0; n < 4; ++n) {
        const int c = bcol + wc * 64 + n * 16 + lg;
        const float bval = bias[c];
#pragma unroll
        for (int m = 0; m < 4; ++m) {
            const int r0 = brow + wr * 64 + m * 16 + hg * 4;
#pragma unroll
            for (int r = 0; r < 4; ++r) {
                const float val = acc[m][n][r] + bval;
                const int row = r0 + r;
                if (z == 0) {
                    Qp[(size_t)row * 768 + c] = (f16)val;
                } else if (z == 1) {
                    Kp[(size_t)row * 768 + c] = (f16)val;
                } else {
                    const int bb = row >> 11, t = row & 2047;
                    const int hh = c >> 6, d = c & 63;
                    // permute t within each 32-block so PV B-frags load linearly:
                    // j=t&15, cc=(t>>4)&1 -> pos = (j>>2)*8 + cc*4 + (j&3)
                    const int j = t & 15, cc = (t >> 4) & 1;
                    const int tp = (t & ~31) | ((j >> 2) * 8 + cc * 4 + (j & 3));
                    Vt[(((size_t)(bb * 12 + hh)) * 64 + d) * 2048 + tp] = (f16)val;
                }
            }
        }
    }
}

// ---------------- output projection ----------------
__global__ __launch_bounds__(256) void out_proj(
    const f16* __restrict__ ctx, const f16* __restrict__ woh,
    const float* __restrict__ bo, float* __restrict__ out)
{
    __shared__ f16 As[128 * 32], Bs[128 * 32];
    const int brow = blockIdx.y * 128, bcol = blockIdx.x * 128;
    f32x4 acc[4][4];
    const f32x4 z4 = { 0.f, 0.f, 0.f, 0.f };
#pragma unroll
    for (int m = 0; m < 4; ++m)
#pragma unroll
        for (int n = 0; n < 4; ++n) acc[m][n] = z4;

    gemm_tile_mainloop(ctx, woh, brow, bcol, As, Bs, acc);

    const int tid = threadIdx.x, w = tid >> 6, lane = tid & 63;
    const int lg = lane & 15, hg = lane >> 4, wr = w >> 1, wc = w & 1;
#pragma unroll
    for (int n = 0; n < 4; ++n) {
        const int c = bcol + wc * 64 + n * 16 + lg;
        const float bval = bo[c];
#pragma unroll
        for (int m = 0; m < 4; ++m) {
            const int r0 = brow + wr * 64 + m * 16 + hg * 4;
#pragma unroll
            for (int r = 0; r < 4; ++r)
                out[(size_t)(r0 + r) * 768 + c] = acc[m][n][r] + bval;
        }
    }
}

// ---------------- fused attention: QK^T (swapped) + softmax (no-max) + PV ----------------
// No LDS, no barriers. Writes ctx (f16) and 1/l (for attn_mean).
__global__ __launch_bounds__(256) void attn_out(
    const f16* __restrict__ Qp, const f16* __restrict__ Kp, const f16* __restrict__ Vt,
    float* __restrict__ l_inv, f16* __restrict__ ctx)
{
    const int qt = blockIdx.x, h = blockIdx.y, b = blockIdx.z;
    const int tid = threadIdx.x, w = tid >> 6, lane = tid & 63;
    const int lg = lane & 15, hg = lane >> 4;

    const size_t qrow0 = (size_t)b * 2048 + qt * 64 + w * 16;
    const int hcol = h * 64;
    const f16* qbase = Qp + (qrow0 + lg) * 768 + hcol + hg * 8;
    const f16x8 bq0 = *(const f16x8*)(qbase);
    const f16x8 bq1 = *(const f16x8*)(qbase + 32);

    const size_t kbase = (size_t)b * 2048;
    const f16* vrow = Vt + ((size_t)(b * 12 + h)) * 64 * 2048 + (size_t)lg * 2048 + hg * 8;

    const f32x4 z4 = { 0.f, 0.f, 0.f, 0.f };
    f32x4 oacc[4];
#pragma unroll
    for (int n = 0; n < 4; ++n) oacc[n] = z4;
    float lsum = 0.f;

    f16x8 kA[4][2], kB[4][2], vf[4][2];

#define LOADK(DST, KT) do { \
    const f16* kr_ = Kp + (kbase + (size_t)(KT) * 64 + lg) * 768 + hcol + hg * 8; \
    _Pragma("unroll") \
    for (int n_ = 0; n_ < 4; ++n_) { \
        DST[n_][0] = *(const f16x8*)(kr_ + n_ * 16 * 768); \
        DST[n_][1] = *(const f16x8*)(kr_ + n_ * 16 * 768 + 32); } } while (0)

#define LOADV(KT) do { \
    const f16* vr_ = vrow + (KT) * 64; \
    _Pragma("unroll") \
    for (int n_ = 0; n_ < 4; ++n_) { \
        vf[n_][0] = *(const f16x8*)(vr_ + n_ * 16 * 2048); \
        vf[n_][1] = *(const f16x8*)(vr_ + n_ * 16 * 2048 + 32); } } while (0)

#define AOBODY(KF) do { \
    f32x4 sa0 = z4, sa1 = z4, sa2 = z4, sa3 = z4; \
    sa0 = MFMA16(KF[0][0], bq0, sa0); sa0 = MFMA16(KF[0][1], bq1, sa0); \
    sa1 = MFMA16(KF[1][0], bq0, sa1); sa1 = MFMA16(KF[1][1], bq1, sa1); \
    sa2 = MFMA16(KF[2][0], bq0, sa2); sa2 = MFMA16(KF[2][1], bq1, sa2); \
    sa3 = MFMA16(KF[3][0], bq0, sa3); sa3 = MFMA16(KF[3][1], bq1, sa3); \
    const float p0  = exp2f(sa0[0] * SC2), p1  = exp2f(sa0[1] * SC2); \
    const float p2  = exp2f(sa0[2] * SC2), p3  = exp2f(sa0[3] * SC2); \
    const float p4  = exp2f(sa1[0] * SC2), p5  = exp2f(sa1[1] * SC2); \
    const float p6  = exp2f(sa1[2] * SC2), p7  = exp2f(sa1[3] * SC2); \
    const float p8  = exp2f(sa2[0] * SC2), p9  = exp2f(sa2[1] * SC2); \
    const float p10 = exp2f(sa2[2] * SC2), p11 = exp2f(sa2[3] * SC2); \
    const float p12 = exp2f(sa3[0] * SC2), p13 = exp2f(sa3[1] * SC2); \
    const float p14 = exp2f(sa3[2] * SC2), p15 = exp2f(sa3[3] * SC2); \
    PA pa0, pa1; \
    pa0.h[0] = CVTPK(p0, p1);   pa0.h[1] = CVTPK(p2, p3); \
    pa0.h[2] = CVTPK(p4, p5);   pa0.h[3] = CVTPK(p6, p7); \
    pa1.h[0] = CVTPK(p8, p9);   pa1.h[1] = CVTPK(p10, p11); \
    pa1.h[2] = CVTPK(p12, p13); pa1.h[3] = CVTPK(p14, p15); \
    lsum += (((p0 + p1) + (p2 + p3)) + ((p4 + p5) + (p6 + p7))) \
          + (((p8 + p9) + (p10 + p11)) + ((p12 + p13) + (p14 + p15))); \
    oacc[0] = MFMA16(pa0.v, vf[0][0], oacc[0]); oacc[0] = MFMA16(pa1.v, vf[0][1], oacc[0]); \
    oacc[1] = MFMA16(pa0.v, vf[1][0], oacc[1]); oacc[1] = MFMA16(pa1.v, vf[1][1], oacc[1]); \
    oacc[2] = MFMA16(pa0.v, vf[2][0], oacc[2]); oacc[2] = MFMA16(pa1.v, vf[2][1], oacc[2]); \
    oacc[3] = MFMA16(pa0.v, vf[3][0], oacc[3]); oacc[3] = MFMA16(pa1.v, vf[3][1], oacc[3]); \
} while (0)

    LOADK(kA, 0);
    for (int kt = 0; kt < 32; kt += 2) {
        LOADK(kB, kt + 1);
        LOADV(kt);
        AOBODY(kA);
        LOADK(kA, (kt + 2) & 31);
        LOADV(kt + 1);
        AOBODY(kB);
    }
#undef LOADK
#undef LOADV
#undef AOBODY

    lsum += __shfl_xor(lsum, 16);
    lsum += __shfl_xor(lsum, 32);
    const float iv = 1.f / lsum;
    if (hg == 0)
        l_inv[((size_t)(b * 12 + h)) * 2048 + qt * 64 + w * 16 + lg] = iv;
    float ivr[4];
#pragma unroll
    for (int r = 0; r < 4; ++r) ivr[r] = __shfl(iv, hg * 4 + r);
#pragma unroll
    for (int n = 0; n < 4; ++n)
#pragma unroll
        for (int r = 0; r < 4; ++r)
            ctx[(qrow0 + hg * 4 + r) * 768 + hcol + n * 16 + lg] = (f16)(oacc[n][r] * ivr[r]);
}

// ---------------- attn mean over heads (recompute QK, normalize by 1/l) ----------------
__global__ __launch_bounds__(256) void attn_mean(
    const f16* __restrict__ Qp, const f16* __restrict__ Kp,
    const float* __restrict__ l_inv, float* __restrict__ om)
{
    const int kt = blockIdx.x, qt = blockIdx.y, b = blockIdx.z;
    const int tid = threadIdx.x, w = tid >> 6, lane = tid & 63;
    const int lg = lane & 15, hg = lane >> 4;
    const size_t qrow0 = (size_t)b * 2048 + qt * 64 + w * 16;
    const size_t krow0 = (size_t)b * 2048 + kt * 64;

    float macc[4][4];
#pragma unroll
    for (int n = 0; n < 4; ++n)
#pragma unroll
        for (int r = 0; r < 4; ++r) macc[n][r] = 0.f;

    const f32x4 z4 = { 0.f, 0.f, 0.f, 0.f };
    f16x8 qA0, qA1, qB0, qB1;
    f16x8 kA[4][2], kB[4][2];
    float4 ivA, ivB;

#define LOADH(Q0, Q1, KS, IVS, H) do { \
    const f16* qb_ = Qp + (qrow0 + lg) * 768 + (H) * 64 + hg * 8; \
    Q0 = *(const f16x8*)(qb_); Q1 = *(const f16x8*)(qb_ + 32); \
    const f16* kr_ = Kp + (krow0 + lg) * 768 + (H) * 64 + hg * 8; \
    _Pragma("unroll") \
    for (int n_ = 0; n_ < 4; ++n_) { \
        KS[n_][0] = *(const f16x8*)(kr_ + n_ * 16 * 768); \
        KS[n_][1] = *(const f16x8*)(kr_ + n_ * 16 * 768 + 32); } \
    IVS = *(const float4*)(l_inv + ((size_t)(b * 12 + (H))) * 2048 + qt * 64 + w * 16 + hg * 4); \
} while (0)

#define MBODY(Q0, Q1, KS, IVS) do { \
    f32x4 sa0 = z4, sa1 = z4, sa2 = z4, sa3 = z4; \
    sa0 = MFMA16(Q0, KS[0][0], sa0); sa0 = MFMA16(Q1, KS[0][1], sa0); \
    sa1 = MFMA16(Q0, KS[1][0], sa1); sa1 = MFMA16(Q1, KS[1][1], sa1); \
    sa2 = MFMA16(Q0, KS[2][0], sa2); sa2 = MFMA16(Q1, KS[2][1], sa2); \
    sa3 = MFMA16(Q0, KS[3][0], sa3); sa3 = MFMA16(Q1, KS[3][1], sa3); \
    _Pragma("unroll") \
    for (int r_ = 0; r_ < 4; ++r_) { \
        const float ivv = ((const float*)&IVS)[r_]; \
        macc[0][r_] += exp2f(sa0[r_] * SC2) * ivv; \
        macc[1][r_] += exp2f(sa1[r_] * SC2) * ivv; \
        macc[2][r_] += exp2f(sa2[r_] * SC2) * ivv; \
        macc[3][r_] += exp2f(sa3[r_] * SC2) * ivv; } \
} while (0)

    LOADH(qA0, qA1, kA, ivA, 0);
    for (int h = 0; h < 12; h += 2) {
        LOADH(qB0, qB1, kB, ivB, h + 1);
        MBODY(qA0, qA1, kA, ivA);
        LOADH(qA0, qA1, kA, ivA, (h + 2 < 12) ? (h + 2) : 0);
        MBODY(qB0, qB1, kB, ivB);
    }
#undef LOADH
#undef MBODY

#pragma unroll
    for (int n = 0; n < 4; ++n)
#pragma unroll
        for (int r = 0; r < 4; ++r) {
            const size_t row = qrow0 + hg * 4 + r;
            const size_t col = (size_t)kt * 64 + n * 16 + lg;
            om[row * 2048 + col] = macc[n][r] * (1.0f / 12.0f);
        }
}

// ---------------- launch ----------------
extern "C" void kernel_launch(void* const* d_in, const int* in_sizes, int n_in,
                              void* d_out, int out_size, void* d_ws, size_t ws_size,
                              hipStream_t stream) {
    const float* q  = (const float*)d_in[0];
    const float* k  = (const float*)d_in[1];
    const float* v  = (const float*)d_in[2];
    const float* Wq = (const float*)d_in[3];
    const float* bq = (const float*)d_in[4];
    const float* Wk = (const float*)d_in[5];
    const float* bk = (const float*)d_in[6];
    const float* Wv = (const float*)d_in[7];
    const float* bv = (const float*)d_in[8];
    const float* Wo = (const float*)d_in[9];
    const float* bo = (const float*)d_in[10];
    float* out = (float*)d_out;

    char* ws = (char*)d_ws;
    const size_t SZ_IN = (size_t)Mc * Dc * 2;
    const size_t SZ_W  = (size_t)Dc * Dc * 2;
    f16* qh  = (f16*)(ws);
    f16* kh  = (f16*)(ws + SZ_IN);
    f16* vh  = (f16*)(ws + 2 * SZ_IN);
    f16* wqh = (f16*)(ws + 3 * SZ_IN);
    f16* wkh = (f16*)(ws + 3 * SZ_IN + SZ_W);
    f16* wvh = (f16*)(ws + 3 * SZ_IN + 2 * SZ_W);
    f16* woh = (f16*)(ws + 3 * SZ_IN + 3 * SZ_W);
    f16* Qp  = (f16*)(ws + 3 * SZ_IN + 4 * SZ_W);
    f16* Kp  = (f16*)(ws + 4 * SZ_IN + 4 * SZ_W);
    f16* Vt  = (f16*)(ws + 5 * SZ_IN + 4 * SZ_W);
    f16* ctx = qh;                 // dead-buffer reuse
    float* l_inv = (float*)kh;     // dead-buffer reuse

    conv_all<<<dim3(11520), dim3(256), 0, stream>>>(q, k, v, Wq, Wk, Wv, Wo,
                                                    qh, kh, vh, wqh, wkh, wvh, woh);
    qkv_proj<<<dim3(6, 32, 3), dim3(256), 0, stream>>>(qh, kh, vh, wqh, wkh, wvh,
                                                       bq, bk, bv, Qp, Kp, Vt);
    attn_out<<<dim3(32, 12, 2), dim3(256), 0, stream>>>(Qp, Kp, Vt, l_inv, ctx);
    attn_mean<<<dim3(32, 32, 2), dim3(256), 0, stream>>>(Qp, Kp, l_inv,
                                                         out + (size_t)Mc * Dc);
    out_proj<<<dim3(6, 32, 1), dim3(256), 0, stream>>>(ctx, woh, bo, out);
}

// Round 4
// 164.530 us; speedup vs baseline: 2.8904x; 2.1960x over previous
//
#include <hip/hip_runtime.h>
#include <hip/hip_fp16.h>
#include <stdint.h>

typedef _Float16 f16;
typedef _Float16 f16x8 __attribute__((ext_vector_type(8)));
typedef _Float16 f16x4v __attribute__((ext_vector_type(4)));
typedef __fp16 h16x2 __attribute__((ext_vector_type(2)));   // cvt_pkrtz return type
typedef float f32x4 __attribute__((ext_vector_type(4)));

#define MFMA16(a,b,c) __builtin_amdgcn_mfma_f32_16x16x32_f16(a,b,c,0,0,0)
#define CVTPK(a,b) __builtin_amdgcn_cvt_pkrtz(a,b)

typedef __attribute__((address_space(1))) void gvoid_t;
typedef __attribute__((address_space(3))) void svoid_t;
#define AS1(p) ((gvoid_t*)(uintptr_t)(p))
#define AS3(p) ((svoid_t*)(uint32_t)(uintptr_t)(p))

static constexpr int Bc = 2, Tc = 2048, Dc = 768, Hc = 12;
static constexpr int Mc = Bc * Tc;                      // 4096
static constexpr float SC2 = 0.18033688011112042f;      // (1/8) * log2(e)

union PA { f16x8 v; h16x2 h[4]; };

// Swizzled LDS fragment read: tile = 64 rows x 8 chunks of 16B, chunk ^= row&7.
// ROW16 = n*16 (row = ROW16+lg, row&7 == lg&7); HALF in {0,1}; chunk = HALF*4+hg.
#define FRAG(BASE, ROW16, HALF) \
    (*(const f16x8*)((const char*)(BASE) + \
        (((((ROW16) + lg) * 8) + ((((HALF) * 4 + hg)) ^ (lg & 7))) * 16)))

// ---------------- f32 -> f16 conversion (all inputs + weights) ----------------
__global__ __launch_bounds__(256) void conv_all(
    const float* __restrict__ q, const float* __restrict__ k, const float* __restrict__ v,
    const float* __restrict__ wq, const float* __restrict__ wk, const float* __restrict__ wv,
    const float* __restrict__ wo,
    f16* __restrict__ qh, f16* __restrict__ kh, f16* __restrict__ vh,
    f16* __restrict__ wqh, f16* __restrict__ wkh, f16* __restrict__ wvh, f16* __restrict__ woh)
{
    const int NI = (Mc * Dc) / 4;
    const int NW = (Dc * Dc) / 4;
    int i = blockIdx.x * 256 + threadIdx.x;
    if (i >= 3 * NI + 4 * NW) return;
    const float4* src; f16* dst; int j;
    if (i < 3 * NI) {
        int a = i / NI; j = i - a * NI;
        src = (const float4*)(a == 0 ? q : (a == 1 ? k : v));
        dst = (a == 0 ? qh : (a == 1 ? kh : vh));
    } else {
        int t = i - 3 * NI;
        int a = t / NW; j = t - a * NW;
        src = (const float4*)(a == 0 ? wq : (a == 1 ? wk : (a == 2 ? wv : wo)));
        dst = (a == 0 ? wqh : (a == 1 ? wkh : (a == 2 ? wvh : woh)));
    }
    float4 f = src[j];
    f16x4v o = { (f16)f.x, (f16)f.y, (f16)f.z, (f16)f.w };
    *(f16x4v*)(dst + 4 * j) = o;
}

// ---------------- 128x128 GEMM mainloop: C = A @ W^T over K=768 ----------------
__device__ __forceinline__ void gemm_tile_mainloop(
    const f16* __restrict__ A, const f16* __restrict__ W,
    int brow, int bcol, f16* As, f16* Bs, f32x4 acc[4][4])
{
    const int tid = threadIdx.x;
    const int w = tid >> 6, lane = tid & 63;
    const int lg = lane & 15, hg = lane >> 4;
    const int wr = w >> 1, wc = w & 1;

    for (int kt = 0; kt < 768 / 32; ++kt) {
        const int k0 = kt * 32;
#pragma unroll
        for (int j = 0; j < 2; ++j) {
            int p = (w * 2 + j) * 1024 + lane * 16;
            int r = p >> 6;
            int ke = (p & 63) >> 1;
            __builtin_amdgcn_global_load_lds(AS1(A + (size_t)(brow + r) * 768 + k0 + ke),
                                             AS3((char*)As + (w * 2 + j) * 1024), 16, 0, 0);
            __builtin_amdgcn_global_load_lds(AS1(W + (size_t)(bcol + r) * 768 + k0 + ke),
                                             AS3((char*)Bs + (w * 2 + j) * 1024), 16, 0, 0);
        }
        __syncthreads();
        f16x8 af[4], bf[4];
#pragma unroll
        for (int m = 0; m < 4; ++m)
            af[m] = *(const f16x8*)(As + (wr * 64 + m * 16 + lg) * 32 + hg * 8);
#pragma unroll
        for (int n = 0; n < 4; ++n)
            bf[n] = *(const f16x8*)(Bs + (wc * 64 + n * 16 + lg) * 32 + hg * 8);
#pragma unroll
        for (int m = 0; m < 4; ++m)
#pragma unroll
            for (int n = 0; n < 4; ++n)
                acc[m][n] = MFMA16(af[m], bf[n], acc[m][n]);
        __syncthreads();
    }
}

// ---------------- QKV projections (z: 0=Q, 1=K, 2=V-transposed+permuted) ----------------
__global__ __launch_bounds__(256) void qkv_proj(
    const f16* __restrict__ qh, const f16* __restrict__ kh, const f16* __restrict__ vh,
    const f16* __restrict__ wqh, const f16* __restrict__ wkh, const f16* __restrict__ wvh,
    const float* __restrict__ bq, const float* __restrict__ bk, const float* __restrict__ bv,
    f16* __restrict__ Qp, f16* __restrict__ Kp, f16* __restrict__ Vt)
{
    __shared__ f16 As[128 * 32], Bs[128 * 32];
    const int z = blockIdx.z;
    const f16* A = (z == 0) ? qh : (z == 1) ? kh : vh;
    const f16* W = (z == 0) ? wqh : (z == 1) ? wkh : wvh;
    const float* bias = (z == 0) ? bq : (z == 1) ? bk : bv;
    const int brow = blockIdx.y * 128, bcol = blockIdx.x * 128;

    f32x4 acc[4][4];
    const f32x4 z4 = { 0.f, 0.f, 0.f, 0.f };
#pragma unroll
    for (int m = 0; m < 4; ++m)
#pragma unroll
        for (int n = 0; n < 4; ++n) acc[m][n] = z4;

    gemm_tile_mainloop(A, W, brow, bcol, As, Bs, acc);

    const int tid = threadIdx.x, w = tid >> 6, lane = tid & 63;
    const int lg = lane & 15, hg = lane >> 4, wr = w >> 1, wc = w & 1;
#pragma unroll
    for (int n = 0; n < 4; ++n) {
        const int c = bcol + wc * 64 + n * 16 + lg;
        const float bval = bias[c];
#pragma unroll
        for (int m = 0; m < 4; ++m) {
            const int r0 = brow + wr * 64 + m * 16 + hg * 4;
#pragma unroll
            for (int r = 0; r < 4; ++r) {
                const float val = acc[m][n][r] + bval;
                const int row = r0 + r;
                if (z == 0) {
                    Qp[(size_t)row * 768 + c] = (f16)val;
                } else if (z == 1) {
                    Kp[(size_t)row * 768 + c] = (f16)val;
                } else {
                    const int bb = row >> 11, t = row & 2047;
                    const int hh = c >> 6, d = c & 63;
                    // permute t within each 32-block so PV B-frags load linearly:
                    const int j = t & 15, cc = (t >> 4) & 1;
                    const int tp = (t & ~31) | ((j >> 2) * 8 + cc * 4 + (j & 3));
                    Vt[(((size_t)(bb * 12 + hh)) * 64 + d) * 2048 + tp] = (f16)val;
                }
            }
        }
    }
}

// ---------------- output projection ----------------
__global__ __launch_bounds__(256) void out_proj(
    const f16* __restrict__ ctx, const f16* __restrict__ woh,
    const float* __restrict__ bo, float* __restrict__ out)
{
    __shared__ f16 As[128 * 32], Bs[128 * 32];
    const int brow = blockIdx.y * 128, bcol = blockIdx.x * 128;
    f32x4 acc[4][4];
    const f32x4 z4 = { 0.f, 0.f, 0.f, 0.f };
#pragma unroll
    for (int m = 0; m < 4; ++m)
#pragma unroll
        for (int n = 0; n < 4; ++n) acc[m][n] = z4;

    gemm_tile_mainloop(ctx, woh, brow, bcol, As, Bs, acc);

    const int tid = threadIdx.x, w = tid >> 6, lane = tid & 63;
    const int lg = lane & 15, hg = lane >> 4, wr = w >> 1, wc = w & 1;
#pragma unroll
    for (int n = 0; n < 4; ++n) {
        const int c = bcol + wc * 64 + n * 16 + lg;
        const float bval = bo[c];
#pragma unroll
        for (int m = 0; m < 4; ++m) {
            const int r0 = brow + wr * 64 + m * 16 + hg * 4;
#pragma unroll
            for (int r = 0; r < 4; ++r)
                out[(size_t)(r0 + r) * 768 + c] = acc[m][n][r] + bval;
        }
    }
}

// ---------------- fused attention: QK^T (swapped) + softmax (no-max) + PV ----------------
// K/V tiles LDS-staged (double-buffered, chunk-XOR swizzle). Writes ctx and 1/l.
__global__ __launch_bounds__(256) void attn_out(
    const f16* __restrict__ Qp, const f16* __restrict__ Kp, const f16* __restrict__ Vt,
    float* __restrict__ l_inv, f16* __restrict__ ctx)
{
    __shared__ f16 Kbuf[2][4096];   // [64 krow][8 chunks*8 f16], swizzled
    __shared__ f16 Vbuf[2][4096];   // [64 d]   [8 chunks*8 f16], swizzled

    const int qt = blockIdx.x, h = blockIdx.y, b = blockIdx.z;
    const int tid = threadIdx.x, w = tid >> 6, lane = tid & 63;
    const int lg = lane & 15, hg = lane >> 4;
    const int wbase16 = (tid & ~63) * 16;   // wave-uniform LDS byte base per call

    const size_t qrow0 = (size_t)b * 2048 + qt * 64 + w * 16;
    const int hcol = h * 64;
    const f16* qbase = Qp + (qrow0 + lg) * 768 + hcol + hg * 8;
    const f16x8 bq0 = *(const f16x8*)(qbase);
    const f16x8 bq1 = *(const f16x8*)(qbase + 32);

    const size_t kbase = (size_t)b * 2048;
    const f16* Vg = Vt + ((size_t)(b * 12 + h)) * 64 * 2048;

    const f32x4 z4 = { 0.f, 0.f, 0.f, 0.f };
    f32x4 oacc[4];
#pragma unroll
    for (int n = 0; n < 4; ++n) oacc[n] = z4;
    float lsum = 0.f;

#define STAGE_KV(KT_, BUF) do { \
    _Pragma("unroll") \
    for (int j_ = 0; j_ < 2; ++j_) { \
        const int p_ = j_ * 256 + tid; \
        const int row_ = p_ >> 3, c_ = (p_ & 7) ^ (row_ & 7); \
        __builtin_amdgcn_global_load_lds( \
            AS1(Kp + (kbase + (size_t)(KT_) * 64 + row_) * 768 + hcol + c_ * 8), \
            AS3((char*)&Kbuf[BUF][0] + j_ * 4096 + wbase16), 16, 0, 0); \
        __builtin_amdgcn_global_load_lds( \
            AS1(Vg + (size_t)row_ * 2048 + (KT_) * 64 + c_ * 8), \
            AS3((char*)&Vbuf[BUF][0] + j_ * 4096 + wbase16), 16, 0, 0); \
    } } while (0)

#define AOBODY(CUR) do { \
    const f16* Kb_ = &Kbuf[CUR][0]; const f16* Vb_ = &Vbuf[CUR][0]; \
    f32x4 sa0 = z4, sa1 = z4, sa2 = z4, sa3 = z4; \
    sa0 = MFMA16(FRAG(Kb_, 0,  0), bq0, sa0); sa0 = MFMA16(FRAG(Kb_, 0,  1), bq1, sa0); \
    sa1 = MFMA16(FRAG(Kb_, 16, 0), bq0, sa1); sa1 = MFMA16(FRAG(Kb_, 16, 1), bq1, sa1); \
    sa2 = MFMA16(FRAG(Kb_, 32, 0), bq0, sa2); sa2 = MFMA16(FRAG(Kb_, 32, 1), bq1, sa2); \
    sa3 = MFMA16(FRAG(Kb_, 48, 0), bq0, sa3); sa3 = MFMA16(FRAG(Kb_, 48, 1), bq1, sa3); \
    const float p0  = exp2f(sa0[0] * SC2), p1  = exp2f(sa0[1] * SC2); \
    const float p2  = exp2f(sa0[2] * SC2), p3  = exp2f(sa0[3] * SC2); \
    const float p4  = exp2f(sa1[0] * SC2), p5  = exp2f(sa1[1] * SC2); \
    const float p6  = exp2f(sa1[2] * SC2), p7  = exp2f(sa1[3] * SC2); \
    const float p8  = exp2f(sa2[0] * SC2), p9  = exp2f(sa2[1] * SC2); \
    const float p10 = exp2f(sa2[2] * SC2), p11 = exp2f(sa2[3] * SC2); \
    const float p12 = exp2f(sa3[0] * SC2), p13 = exp2f(sa3[1] * SC2); \
    const float p14 = exp2f(sa3[2] * SC2), p15 = exp2f(sa3[3] * SC2); \
    PA pa0, pa1; \
    pa0.h[0] = CVTPK(p0, p1);   pa0.h[1] = CVTPK(p2, p3); \
    pa0.h[2] = CVTPK(p4, p5);   pa0.h[3] = CVTPK(p6, p7); \
    pa1.h[0] = CVTPK(p8, p9);   pa1.h[1] = CVTPK(p10, p11); \
    pa1.h[2] = CVTPK(p12, p13); pa1.h[3] = CVTPK(p14, p15); \
    lsum += (((p0 + p1) + (p2 + p3)) + ((p4 + p5) + (p6 + p7))) \
          + (((p8 + p9) + (p10 + p11)) + ((p12 + p13) + (p14 + p15))); \
    oacc[0] = MFMA16(pa0.v, FRAG(Vb_, 0,  0), oacc[0]); oacc[0] = MFMA16(pa1.v, FRAG(Vb_, 0,  1), oacc[0]); \
    oacc[1] = MFMA16(pa0.v, FRAG(Vb_, 16, 0), oacc[1]); oacc[1] = MFMA16(pa1.v, FRAG(Vb_, 16, 1), oacc[1]); \
    oacc[2] = MFMA16(pa0.v, FRAG(Vb_, 32, 0), oacc[2]); oacc[2] = MFMA16(pa1.v, FRAG(Vb_, 32, 1), oacc[2]); \
    oacc[3] = MFMA16(pa0.v, FRAG(Vb_, 48, 0), oacc[3]); oacc[3] = MFMA16(pa1.v, FRAG(Vb_, 48, 1), oacc[3]); \
} while (0)

    STAGE_KV(0, 0);
    __syncthreads();
    for (int kt = 0; kt < 32; ++kt) {
        const int cur = kt & 1;
        if (kt < 31) STAGE_KV(kt + 1, cur ^ 1);
        AOBODY(cur);
        __syncthreads();
    }
#undef STAGE_KV
#undef AOBODY

    lsum += __shfl_xor(lsum, 16);
    lsum += __shfl_xor(lsum, 32);
    const float iv = 1.f / lsum;
    if (hg == 0)
        l_inv[((size_t)(b * 12 + h)) * 2048 + qt * 64 + w * 16 + lg] = iv;
    float ivr[4];
#pragma unroll
    for (int r = 0; r < 4; ++r) ivr[r] = __shfl(iv, hg * 4 + r);
#pragma unroll
    for (int n = 0; n < 4; ++n)
#pragma unroll
        for (int r = 0; r < 4; ++r)
            ctx[(qrow0 + hg * 4 + r) * 768 + hcol + n * 16 + lg] = (f16)(oacc[n][r] * ivr[r]);
}

// ---------------- attn mean over heads (recompute QK, normalize by 1/l) ----------------
__global__ __launch_bounds__(256) void attn_mean(
    const f16* __restrict__ Qp, const f16* __restrict__ Kp,
    const float* __restrict__ l_inv, float* __restrict__ om)
{
    __shared__ f16 Qbuf[2][4096];   // [64 qrow][8 chunks], swizzled
    __shared__ f16 Kbuf[2][4096];   // [64 krow][8 chunks], swizzled

    const int kt = blockIdx.x, qt = blockIdx.y, b = blockIdx.z;
    const int tid = threadIdx.x, w = tid >> 6, lane = tid & 63;
    const int lg = lane & 15, hg = lane >> 4;
    const int wbase16 = (tid & ~63) * 16;
    const size_t qrow0 = (size_t)b * 2048 + qt * 64 + w * 16;
    const size_t qtrow = (size_t)b * 2048 + qt * 64;
    const size_t ktrow = (size_t)b * 2048 + kt * 64;

    float macc[4][4];
#pragma unroll
    for (int n = 0; n < 4; ++n)
#pragma unroll
        for (int r = 0; r < 4; ++r) macc[n][r] = 0.f;

    const f32x4 z4 = { 0.f, 0.f, 0.f, 0.f };

#define STAGE_QK(H_, BUF) do { \
    _Pragma("unroll") \
    for (int j_ = 0; j_ < 2; ++j_) { \
        const int p_ = j_ * 256 + tid; \
        const int row_ = p_ >> 3, c_ = (p_ & 7) ^ (row_ & 7); \
        __builtin_amdgcn_global_load_lds( \
            AS1(Qp + (qtrow + row_) * 768 + (H_) * 64 + c_ * 8), \
            AS3((char*)&Qbuf[BUF][0] + j_ * 4096 + wbase16), 16, 0, 0); \
        __builtin_amdgcn_global_load_lds( \
            AS1(Kp + (ktrow + row_) * 768 + (H_) * 64 + c_ * 8), \
            AS3((char*)&Kbuf[BUF][0] + j_ * 4096 + wbase16), 16, 0, 0); \
    } } while (0)

#define MBODY(H_, CUR) do { \
    const f16* Qb_ = &Qbuf[CUR][0]; const f16* Kb_ = &Kbuf[CUR][0]; \
    const f16x8 q0_ = FRAG(Qb_, w * 16, 0), q1_ = FRAG(Qb_, w * 16, 1); \
    f32x4 sa0 = z4, sa1 = z4, sa2 = z4, sa3 = z4; \
    sa0 = MFMA16(q0_, FRAG(Kb_, 0,  0), sa0); sa0 = MFMA16(q1_, FRAG(Kb_, 0,  1), sa0); \
    sa1 = MFMA16(q0_, FRAG(Kb_, 16, 0), sa1); sa1 = MFMA16(q1_, FRAG(Kb_, 16, 1), sa1); \
    sa2 = MFMA16(q0_, FRAG(Kb_, 32, 0), sa2); sa2 = MFMA16(q1_, FRAG(Kb_, 32, 1), sa2); \
    sa3 = MFMA16(q0_, FRAG(Kb_, 48, 0), sa3); sa3 = MFMA16(q1_, FRAG(Kb_, 48, 1), sa3); \
    const float4 iv_ = *(const float4*)(l_inv + ((size_t)(b * 12 + (H_))) * 2048 \
                                        + qt * 64 + w * 16 + hg * 4); \
    _Pragma("unroll") \
    for (int r_ = 0; r_ < 4; ++r_) { \
        const float ivv = ((const float*)&iv_)[r_]; \
        macc[0][r_] += exp2f(sa0[r_] * SC2) * ivv; \
        macc[1][r_] += exp2f(sa1[r_] * SC2) * ivv; \
        macc[2][r_] += exp2f(sa2[r_] * SC2) * ivv; \
        macc[3][r_] += exp2f(sa3[r_] * SC2) * ivv; } \
} while (0)

    STAGE_QK(0, 0);
    __syncthreads();
    for (int h = 0; h < 12; ++h) {
        const int cur = h & 1;
        if (h < 11) STAGE_QK(h + 1, cur ^ 1);
        MBODY(h, cur);
        __syncthreads();
    }
#undef STAGE_QK
#undef MBODY

#pragma unroll
    for (int n = 0; n < 4; ++n)
#pragma unroll
        for (int r = 0; r < 4; ++r) {
            const size_t row = qrow0 + hg * 4 + r;
            const size_t col = (size_t)kt * 64 + n * 16 + lg;
            om[row * 2048 + col] = macc[n][r] * (1.0f / 12.0f);
        }
}

// ---------------- launch ----------------
extern "C" void kernel_launch(void* const* d_in, const int* in_sizes, int n_in,
                              void* d_out, int out_size, void* d_ws, size_t ws_size,
                              hipStream_t stream) {
    const float* q  = (const float*)d_in[0];
    const float* k  = (const float*)d_in[1];
    const float* v  = (const float*)d_in[2];
    const float* Wq = (const float*)d_in[3];
    const float* bq = (const float*)d_in[4];
    const float* Wk = (const float*)d_in[5];
    const float* bk = (const float*)d_in[6];
    const float* Wv = (const float*)d_in[7];
    const float* bv = (const float*)d_in[8];
    const float* Wo = (const float*)d_in[9];
    const float* bo = (const float*)d_in[10];
    float* out = (float*)d_out;

    char* ws = (char*)d_ws;
    const size_t SZ_IN = (size_t)Mc * Dc * 2;
    const size_t SZ_W  = (size_t)Dc * Dc * 2;
    f16* qh  = (f16*)(ws);
    f16* kh  = (f16*)(ws + SZ_IN);
    f16* vh  = (f16*)(ws + 2 * SZ_IN);
    f16* wqh = (f16*)(ws + 3 * SZ_IN);
    f16* wkh = (f16*)(ws + 3 * SZ_IN + SZ_W);
    f16* wvh = (f16*)(ws + 3 * SZ_IN + 2 * SZ_W);
    f16* woh = (f16*)(ws + 3 * SZ_IN + 3 * SZ_W);
    f16* Qp  = (f16*)(ws + 3 * SZ_IN + 4 * SZ_W);
    f16* Kp  = (f16*)(ws + 4 * SZ_IN + 4 * SZ_W);
    f16* Vt  = (f16*)(ws + 5 * SZ_IN + 4 * SZ_W);
    f16* ctx = qh;                 // dead-buffer reuse
    float* l_inv = (float*)kh;     // dead-buffer reuse

    conv_all<<<dim3(11520), dim3(256), 0, stream>>>(q, k, v, Wq, Wk, Wv, Wo,
                                                    qh, kh, vh, wqh, wkh, wvh, woh);
    qkv_proj<<<dim3(6, 32, 3), dim3(256), 0, stream>>>(qh, kh, vh, wqh, wkh, wvh,
                                                       bq, bk, bv, Qp, Kp, Vt);
    attn_out<<<dim3(32, 12, 2), dim3(256), 0, stream>>>(Qp, Kp, Vt, l_inv, ctx);
    attn_mean<<<dim3(32, 32, 2), dim3(256), 0, stream>>>(Qp, Kp, l_inv,
                                                         out + (size_t)Mc * Dc);
    out_proj<<<dim3(6, 32, 1), dim3(256), 0, stream>>>(ctx, woh, bo, out);
}

// Round 5
// 145.873 us; speedup vs baseline: 3.2600x; 1.1279x over previous
//
#include <hip/hip_runtime.h>
#include <hip/hip_fp16.h>
#include <stdint.h>

typedef _Float16 f16;
typedef _Float16 f16x8 __attribute__((ext_vector_type(8)));
typedef _Float16 f16x4v __attribute__((ext_vector_type(4)));
typedef __fp16 h16x2 __attribute__((ext_vector_type(2)));   // cvt_pkrtz return type
typedef float f32x4 __attribute__((ext_vector_type(4)));

#define MFMA16(a,b,c) __builtin_amdgcn_mfma_f32_16x16x32_f16(a,b,c,0,0,0)
#define CVTPK(a,b) __builtin_amdgcn_cvt_pkrtz(a,b)

#if __has_builtin(__builtin_amdgcn_exp2f)
#define EXP2(x) __builtin_amdgcn_exp2f(x)
#else
#define EXP2(x) exp2f(x)
#endif

static __device__ __forceinline__ float dot2acc(h16x2 a, float c) {
#if __has_builtin(__builtin_amdgcn_fdot2)
    const h16x2 one = { (__fp16)1.f, (__fp16)1.f };
    return __builtin_amdgcn_fdot2(a, one, c, false);
#else
    return c + (float)a[0] + (float)a[1];
#endif
}

typedef __attribute__((address_space(1))) void gvoid_t;
typedef __attribute__((address_space(3))) void svoid_t;
#define AS1(p) ((gvoid_t*)(uintptr_t)(p))
#define AS3(p) ((svoid_t*)(uint32_t)(uintptr_t)(p))

static constexpr int Bc = 2, Tc = 2048, Dc = 768, Hc = 12;
static constexpr int Mc = Bc * Tc;                      // 4096
static constexpr float SC2 = 0.18033688011112042f;      // (1/8) * log2(e), folded into Wq/bq

union PA { f16x8 v; h16x2 h[4]; };

// Swizzled LDS fragment read: tile = 64 rows x 8 chunks of 16B, chunk ^= row&7.
#define FRAG(BASE, ROW16, HALF) \
    (*(const f16x8*)((const char*)(BASE) + \
        (((((ROW16) + lg) * 8) + ((((HALF) * 4 + hg)) ^ (lg & 7))) * 16)))

// ---------------- f32 -> f16 conversion (all inputs + weights; Wq pre-scaled) ----------------
__global__ __launch_bounds__(256) void conv_all(
    const float* __restrict__ q, const float* __restrict__ k, const float* __restrict__ v,
    const float* __restrict__ wq, const float* __restrict__ wk, const float* __restrict__ wv,
    const float* __restrict__ wo,
    f16* __restrict__ qh, f16* __restrict__ kh, f16* __restrict__ vh,
    f16* __restrict__ wqh, f16* __restrict__ wkh, f16* __restrict__ wvh, f16* __restrict__ woh)
{
    const int NI = (Mc * Dc) / 4;
    const int NW = (Dc * Dc) / 4;
    int i = blockIdx.x * 256 + threadIdx.x;
    if (i >= 3 * NI + 4 * NW) return;
    const float4* src; f16* dst; int j; float scl = 1.f;
    if (i < 3 * NI) {
        int a = i / NI; j = i - a * NI;
        src = (const float4*)(a == 0 ? q : (a == 1 ? k : v));
        dst = (a == 0 ? qh : (a == 1 ? kh : vh));
    } else {
        int t = i - 3 * NI;
        int a = t / NW; j = t - a * NW;
        src = (const float4*)(a == 0 ? wq : (a == 1 ? wk : (a == 2 ? wv : wo)));
        dst = (a == 0 ? wqh : (a == 1 ? wkh : (a == 2 ? wvh : woh)));
        if (a == 0) scl = SC2;
    }
    float4 f = src[j];
    f16x4v o = { (f16)(f.x * scl), (f16)(f.y * scl), (f16)(f.z * scl), (f16)(f.w * scl) };
    *(f16x4v*)(dst + 4 * j) = o;
}

// ---------------- 128x128 GEMM mainloop: C = A @ W^T over K=768 ----------------
__device__ __forceinline__ void gemm_tile_mainloop(
    const f16* __restrict__ A, const f16* __restrict__ W,
    int brow, int bcol, f16* As, f16* Bs, f32x4 acc[4][4])
{
    const int tid = threadIdx.x;
    const int w = tid >> 6, lane = tid & 63;
    const int lg = lane & 15, hg = lane >> 4;
    const int wr = w >> 1, wc = w & 1;

    for (int kt = 0; kt < 768 / 32; ++kt) {
        const int k0 = kt * 32;
#pragma unroll
        for (int j = 0; j < 2; ++j) {
            int p = (w * 2 + j) * 1024 + lane * 16;
            int r = p >> 6;
            int ke = (p & 63) >> 1;
            __builtin_amdgcn_global_load_lds(AS1(A + (size_t)(brow + r) * 768 + k0 + ke),
                                             AS3((char*)As + (w * 2 + j) * 1024), 16, 0, 0);
            __builtin_amdgcn_global_load_lds(AS1(W + (size_t)(bcol + r) * 768 + k0 + ke),
                                             AS3((char*)Bs + (w * 2 + j) * 1024), 16, 0, 0);
        }
        __syncthreads();
        f16x8 af[4], bf[4];
#pragma unroll
        for (int m = 0; m < 4; ++m)
            af[m] = *(const f16x8*)(As + (wr * 64 + m * 16 + lg) * 32 + hg * 8);
#pragma unroll
        for (int n = 0; n < 4; ++n)
            bf[n] = *(const f16x8*)(Bs + (wc * 64 + n * 16 + lg) * 32 + hg * 8);
#pragma unroll
        for (int m = 0; m < 4; ++m)
#pragma unroll
            for (int n = 0; n < 4; ++n)
                acc[m][n] = MFMA16(af[m], bf[n], acc[m][n]);
        __syncthreads();
    }
}

// ---------------- QKV projections (z: 0=Q-scaled, 1=K, 2=V-transposed+permuted) ----------------
__global__ __launch_bounds__(256) void qkv_proj(
    const f16* __restrict__ qh, const f16* __restrict__ kh, const f16* __restrict__ vh,
    const f16* __restrict__ wqh, const f16* __restrict__ wkh, const f16* __restrict__ wvh,
    const float* __restrict__ bq, const float* __restrict__ bk, const float* __restrict__ bv,
    f16* __restrict__ Qp, f16* __restrict__ Kp, f16* __restrict__ Vt)
{
    __shared__ f16 As[128 * 32], Bs[128 * 32];
    const int z = blockIdx.z;
    const f16* A = (z == 0) ? qh : (z == 1) ? kh : vh;
    const f16* W = (z == 0) ? wqh : (z == 1) ? wkh : wvh;
    const float* bias = (z == 0) ? bq : (z == 1) ? bk : bv;
    const int brow = blockIdx.y * 128, bcol = blockIdx.x * 128;

    f32x4 acc[4][4];
    const f32x4 z4 = { 0.f, 0.f, 0.f, 0.f };
#pragma unroll
    for (int m = 0; m < 4; ++m)
#pragma unroll
        for (int n = 0; n < 4; ++n) acc[m][n] = z4;

    gemm_tile_mainloop(A, W, brow, bcol, As, Bs, acc);

    const int tid = threadIdx.x, w = tid >> 6, lane = tid & 63;
    const int lg = lane & 15, hg = lane >> 4, wr = w >> 1, wc = w & 1;
#pragma unroll
    for (int n = 0; n < 4; ++n) {
        const int c = bcol + wc * 64 + n * 16 + lg;
        const float bval = (z == 0) ? bias[c] * SC2 : bias[c];
#pragma unroll
        for (int m = 0; m < 4; ++m) {
            const int r0 = brow + wr * 64 + m * 16 + hg * 4;
#pragma unroll
            for (int r = 0; r < 4; ++r) {
                const float val = acc[m][n][r] + bval;
                const int row = r0 + r;
                if (z == 0) {
                    Qp[(size_t)row * 768 + c] = (f16)val;
                } else if (z == 1) {
                    Kp[(size_t)row * 768 + c] = (f16)val;
                } else {
                    const int bb = row >> 11, t = row & 2047;
                    const int hh = c >> 6, d = c & 63;
                    const int j = t & 15, cc = (t >> 4) & 1;
                    const int tp = (t & ~31) | ((j >> 2) * 8 + cc * 4 + (j & 3));
                    Vt[(((size_t)(bb * 12 + hh)) * 64 + d) * 2048 + tp] = (f16)val;
                }
            }
        }
    }
}

// ---------------- output projection ----------------
__global__ __launch_bounds__(256) void out_proj(
    const f16* __restrict__ ctx, const f16* __restrict__ woh,
    const float* __restrict__ bo, float* __restrict__ out)
{
    __shared__ f16 As[128 * 32], Bs[128 * 32];
    const int brow = blockIdx.y * 128, bcol = blockIdx.x * 128;
    f32x4 acc[4][4];
    const f32x4 z4 = { 0.f, 0.f, 0.f, 0.f };
#pragma unroll
    for (int m = 0; m < 4; ++m)
#pragma unroll
        for (int n = 0; n < 4; ++n) acc[m][n] = z4;

    gemm_tile_mainloop(ctx, woh, brow, bcol, As, Bs, acc);

    const int tid = threadIdx.x, w = tid >> 6, lane = tid & 63;
    const int lg = lane & 15, hg = lane >> 4, wr = w >> 1, wc = w & 1;
#pragma unroll
    for (int n = 0; n < 4; ++n) {
        const int c = bcol + wc * 64 + n * 16 + lg;
        const float bval = bo[c];
#pragma unroll
        for (int m = 0; m < 4; ++m) {
            const int r0 = brow + wr * 64 + m * 16 + hg * 4;
#pragma unroll
            for (int r = 0; r < 4; ++r)
                out[(size_t)(r0 + r) * 768 + c] = acc[m][n][r] + bval;
        }
    }
}

// ---------------- fused attention: QK^T (pre-scaled) + softmax (no-max) + PV ----------------
__global__ __launch_bounds__(256) void attn_out(
    const f16* __restrict__ Qp, const f16* __restrict__ Kp, const f16* __restrict__ Vt,
    float* __restrict__ l_inv, f16* __restrict__ ctx)
{
    __shared__ f16 Kbuf[2][4096];   // [64 krow][8 chunks*8 f16], swizzled
    __shared__ f16 Vbuf[2][4096];   // [64 d]   [8 chunks*8 f16], swizzled

    const int qt = blockIdx.x, h = blockIdx.y, b = blockIdx.z;
    const int tid = threadIdx.x, w = tid >> 6, lane = tid & 63;
    const int lg = lane & 15, hg = lane >> 4;
    const int wbase16 = (tid & ~63) * 16;

    const size_t qrow0 = (size_t)b * 2048 + qt * 64 + w * 16;
    const int hcol = h * 64;
    const f16* qbase = Qp + (qrow0 + lg) * 768 + hcol + hg * 8;
    const f16x8 bq0 = *(const f16x8*)(qbase);
    const f16x8 bq1 = *(const f16x8*)(qbase + 32);

    const size_t kbase = (size_t)b * 2048;
    const f16* Vg = Vt + ((size_t)(b * 12 + h)) * 64 * 2048;

    const f32x4 z4 = { 0.f, 0.f, 0.f, 0.f };
    f32x4 oacc[4];
#pragma unroll
    for (int n = 0; n < 4; ++n) oacc[n] = z4;
    float lsum = 0.f;

#define STAGE_KV(KT_, BUF) do { \
    _Pragma("unroll") \
    for (int j_ = 0; j_ < 2; ++j_) { \
        const int p_ = j_ * 256 + tid; \
        const int row_ = p_ >> 3, c_ = (p_ & 7) ^ (row_ & 7); \
        __builtin_amdgcn_global_load_lds( \
            AS1(Kp + (kbase + (size_t)(KT_) * 64 + row_) * 768 + hcol + c_ * 8), \
            AS3((char*)&Kbuf[BUF][0] + j_ * 4096 + wbase16), 16, 0, 0); \
        __builtin_amdgcn_global_load_lds( \
            AS1(Vg + (size_t)row_ * 2048 + (KT_) * 64 + c_ * 8), \
            AS3((char*)&Vbuf[BUF][0] + j_ * 4096 + wbase16), 16, 0, 0); \
    } } while (0)

#define AOBODY(CUR) do { \
    const f16* Kb_ = &Kbuf[CUR][0]; const f16* Vb_ = &Vbuf[CUR][0]; \
    f32x4 sa0 = z4, sa1 = z4, sa2 = z4, sa3 = z4; \
    sa0 = MFMA16(FRAG(Kb_, 0,  0), bq0, sa0); sa0 = MFMA16(FRAG(Kb_, 0,  1), bq1, sa0); \
    sa1 = MFMA16(FRAG(Kb_, 16, 0), bq0, sa1); sa1 = MFMA16(FRAG(Kb_, 16, 1), bq1, sa1); \
    sa2 = MFMA16(FRAG(Kb_, 32, 0), bq0, sa2); sa2 = MFMA16(FRAG(Kb_, 32, 1), bq1, sa2); \
    sa3 = MFMA16(FRAG(Kb_, 48, 0), bq0, sa3); sa3 = MFMA16(FRAG(Kb_, 48, 1), bq1, sa3); \
    const float p0  = EXP2(sa0[0]), p1  = EXP2(sa0[1]); \
    const float p2  = EXP2(sa0[2]), p3  = EXP2(sa0[3]); \
    const float p4  = EXP2(sa1[0]), p5  = EXP2(sa1[1]); \
    const float p6  = EXP2(sa1[2]), p7  = EXP2(sa1[3]); \
    const float p8  = EXP2(sa2[0]), p9  = EXP2(sa2[1]); \
    const float p10 = EXP2(sa2[2]), p11 = EXP2(sa2[3]); \
    const float p12 = EXP2(sa3[0]), p13 = EXP2(sa3[1]); \
    const float p14 = EXP2(sa3[2]), p15 = EXP2(sa3[3]); \
    PA pa0, pa1; \
    pa0.h[0] = CVTPK(p0, p1);   pa0.h[1] = CVTPK(p2, p3); \
    pa0.h[2] = CVTPK(p4, p5);   pa0.h[3] = CVTPK(p6, p7); \
    pa1.h[0] = CVTPK(p8, p9);   pa1.h[1] = CVTPK(p10, p11); \
    pa1.h[2] = CVTPK(p12, p13); pa1.h[3] = CVTPK(p14, p15); \
    float t0_ = 0.f, t1_ = 0.f; \
    t0_ = dot2acc(pa0.h[0], t0_); t0_ = dot2acc(pa0.h[1], t0_); \
    t0_ = dot2acc(pa0.h[2], t0_); t0_ = dot2acc(pa0.h[3], t0_); \
    t1_ = dot2acc(pa1.h[0], t1_); t1_ = dot2acc(pa1.h[1], t1_); \
    t1_ = dot2acc(pa1.h[2], t1_); t1_ = dot2acc(pa1.h[3], t1_); \
    lsum += t0_ + t1_; \
    oacc[0] = MFMA16(pa0.v, FRAG(Vb_, 0,  0), oacc[0]); oacc[0] = MFMA16(pa1.v, FRAG(Vb_, 0,  1), oacc[0]); \
    oacc[1] = MFMA16(pa0.v, FRAG(Vb_, 16, 0), oacc[1]); oacc[1] = MFMA16(pa1.v, FRAG(Vb_, 16, 1), oacc[1]); \
    oacc[2] = MFMA16(pa0.v, FRAG(Vb_, 32, 0), oacc[2]); oacc[2] = MFMA16(pa1.v, FRAG(Vb_, 32, 1), oacc[2]); \
    oacc[3] = MFMA16(pa0.v, FRAG(Vb_, 48, 0), oacc[3]); oacc[3] = MFMA16(pa1.v, FRAG(Vb_, 48, 1), oacc[3]); \
} while (0)

    STAGE_KV(0, 0);
    __syncthreads();
    for (int kt = 0; kt < 32; ++kt) {
        const int cur = kt & 1;
        if (kt < 31) STAGE_KV(kt + 1, cur ^ 1);
        AOBODY(cur);
        __syncthreads();
    }
#undef STAGE_KV
#undef AOBODY

    lsum += __shfl_xor(lsum, 16);
    lsum += __shfl_xor(lsum, 32);
    const float iv = 1.f / lsum;
    if (hg == 0)
        l_inv[((size_t)(b * 12 + h)) * 2048 + qt * 64 + w * 16 + lg] = iv;
    float ivr[4];
#pragma unroll
    for (int r = 0; r < 4; ++r) ivr[r] = __shfl(iv, hg * 4 + r);
#pragma unroll
    for (int n = 0; n < 4; ++n)
#pragma unroll
        for (int r = 0; r < 4; ++r)
            ctx[(qrow0 + hg * 4 + r) * 768 + hcol + n * 16 + lg] = (f16)(oacc[n][r] * ivr[r]);
}

// ---------------- attn mean over heads (recompute QK, normalize by 1/l) ----------------
__global__ __launch_bounds__(256) void attn_mean(
    const f16* __restrict__ Qp, const f16* __restrict__ Kp,
    const float* __restrict__ l_inv, float* __restrict__ om)
{
    __shared__ f16 Qbuf[2][4096];
    __shared__ f16 Kbuf[2][4096];

    const int kt = blockIdx.x, qt = blockIdx.y, b = blockIdx.z;
    const int tid = threadIdx.x, w = tid >> 6, lane = tid & 63;
    const int lg = lane & 15, hg = lane >> 4;
    const int wbase16 = (tid & ~63) * 16;
    const size_t qrow0 = (size_t)b * 2048 + qt * 64 + w * 16;
    const size_t qtrow = (size_t)b * 2048 + qt * 64;
    const size_t ktrow = (size_t)b * 2048 + kt * 64;

    float macc[4][4];
#pragma unroll
    for (int n = 0; n < 4; ++n)
#pragma unroll
        for (int r = 0; r < 4; ++r) macc[n][r] = 0.f;

    const f32x4 z4 = { 0.f, 0.f, 0.f, 0.f };

#define STAGE_QK(H_, BUF) do { \
    _Pragma("unroll") \
    for (int j_ = 0; j_ < 2; ++j_) { \
        const int p_ = j_ * 256 + tid; \
        const int row_ = p_ >> 3, c_ = (p_ & 7) ^ (row_ & 7); \
        __builtin_amdgcn_global_load_lds( \
            AS1(Qp + (qtrow + row_) * 768 + (H_) * 64 + c_ * 8), \
            AS3((char*)&Qbuf[BUF][0] + j_ * 4096 + wbase16), 16, 0, 0); \
        __builtin_amdgcn_global_load_lds( \
            AS1(Kp + (ktrow + row_) * 768 + (H_) * 64 + c_ * 8), \
            AS3((char*)&Kbuf[BUF][0] + j_ * 4096 + wbase16), 16, 0, 0); \
    } } while (0)

#define MBODY(H_, CUR) do { \
    const f16* Qb_ = &Qbuf[CUR][0]; const f16* Kb_ = &Kbuf[CUR][0]; \
    const f16x8 q0_ = FRAG(Qb_, w * 16, 0), q1_ = FRAG(Qb_, w * 16, 1); \
    f32x4 sa0 = z4, sa1 = z4, sa2 = z4, sa3 = z4; \
    sa0 = MFMA16(q0_, FRAG(Kb_, 0,  0), sa0); sa0 = MFMA16(q1_, FRAG(Kb_, 0,  1), sa0); \
    sa1 = MFMA16(q0_, FRAG(Kb_, 16, 0), sa1); sa1 = MFMA16(q1_, FRAG(Kb_, 16, 1), sa1); \
    sa2 = MFMA16(q0_, FRAG(Kb_, 32, 0), sa2); sa2 = MFMA16(q1_, FRAG(Kb_, 32, 1), sa2); \
    sa3 = MFMA16(q0_, FRAG(Kb_, 48, 0), sa3); sa3 = MFMA16(q1_, FRAG(Kb_, 48, 1), sa3); \
    const float4 iv_ = *(const float4*)(l_inv + ((size_t)(b * 12 + (H_))) * 2048 \
                                        + qt * 64 + w * 16 + hg * 4); \
    _Pragma("unroll") \
    for (int r_ = 0; r_ < 4; ++r_) { \
        const float ivv = ((const float*)&iv_)[r_]; \
        macc[0][r_] += EXP2(sa0[r_]) * ivv; \
        macc[1][r_] += EXP2(sa1[r_]) * ivv; \
        macc[2][r_] += EXP2(sa2[r_]) * ivv; \
        macc[3][r_] += EXP2(sa3[r_]) * ivv; } \
} while (0)

    STAGE_QK(0, 0);
    __syncthreads();
    for (int h = 0; h < 12; ++h) {
        const int cur = h & 1;
        if (h < 11) STAGE_QK(h + 1, cur ^ 1);
        MBODY(h, cur);
        __syncthreads();
    }
#undef STAGE_QK
#undef MBODY

#pragma unroll
    for (int n = 0; n < 4; ++n)
#pragma unroll
        for (int r = 0; r < 4; ++r) {
            const size_t row = qrow0 + hg * 4 + r;
            const size_t col = (size_t)kt * 64 + n * 16 + lg;
            om[row * 2048 + col] = macc[n][r] * (1.0f / 12.0f);
        }
}

// ---------------- launch ----------------
extern "C" void kernel_launch(void* const* d_in, const int* in_sizes, int n_in,
                              void* d_out, int out_size, void* d_ws, size_t ws_size,
                              hipStream_t stream) {
    const float* q  = (const float*)d_in[0];
    const float* k  = (const float*)d_in[1];
    const float* v  = (const float*)d_in[2];
    const float* Wq = (const float*)d_in[3];
    const float* bq = (const float*)d_in[4];
    const float* Wk = (const float*)d_in[5];
    const float* bk = (const float*)d_in[6];
    const float* Wv = (const float*)d_in[7];
    const float* bv = (const float*)d_in[8];
    const float* Wo = (const float*)d_in[9];
    const float* bo = (const float*)d_in[10];
    float* out = (float*)d_out;

    char* ws = (char*)d_ws;
    const size_t SZ_IN = (size_t)Mc * Dc * 2;
    const size_t SZ_W  = (size_t)Dc * Dc * 2;
    f16* qh  = (f16*)(ws);
    f16* kh  = (f16*)(ws + SZ_IN);
    f16* vh  = (f16*)(ws + 2 * SZ_IN);
    f16* wqh = (f16*)(ws + 3 * SZ_IN);
    f16* wkh = (f16*)(ws + 3 * SZ_IN + SZ_W);
    f16* wvh = (f16*)(ws + 3 * SZ_IN + 2 * SZ_W);
    f16* woh = (f16*)(ws + 3 * SZ_IN + 3 * SZ_W);
    f16* Qp  = (f16*)(ws + 3 * SZ_IN + 4 * SZ_W);
    f16* Kp  = (f16*)(ws + 4 * SZ_IN + 4 * SZ_W);
    f16* Vt  = (f16*)(ws + 5 * SZ_IN + 4 * SZ_W);
    f16* ctx = qh;                 // dead-buffer reuse
    float* l_inv = (float*)kh;     // dead-buffer reuse

    conv_all<<<dim3(11520), dim3(256), 0, stream>>>(q, k, v, Wq, Wk, Wv, Wo,
                                                    qh, kh, vh, wqh, wkh, wvh, woh);
    qkv_proj<<<dim3(6, 32, 3), dim3(256), 0, stream>>>(qh, kh, vh, wqh, wkh, wvh,
                                                       bq, bk, bv, Qp, Kp, Vt);
    attn_out<<<dim3(32, 12, 2), dim3(256), 0, stream>>>(Qp, Kp, Vt, l_inv, ctx);
    attn_mean<<<dim3(32, 32, 2), dim3(256), 0, stream>>>(Qp, Kp, l_inv,
                                                         out + (size_t)Mc * Dc);
    out_proj<<<dim3(6, 32, 1), dim3(256), 0, stream>>>(ctx, woh, bo, out);
}

// Round 6
// 145.221 us; speedup vs baseline: 3.2747x; 1.0045x over previous
//
#include <hip/hip_runtime.h>
#include <hip/hip_fp16.h>
#include <stdint.h>

typedef _Float16 f16;
typedef _Float16 f16x8 __attribute__((ext_vector_type(8)));
typedef _Float16 f16x4v __attribute__((ext_vector_type(4)));
typedef __fp16 h16x2 __attribute__((ext_vector_type(2)));   // cvt_pkrtz return type
typedef float f32x4 __attribute__((ext_vector_type(4)));
typedef float f32x16 __attribute__((ext_vector_type(16)));

#define MFMA16(a,b,c) __builtin_amdgcn_mfma_f32_16x16x32_f16(a,b,c,0,0,0)
#define MFMA32(a,b,c) __builtin_amdgcn_mfma_f32_32x32x16_f16(a,b,c,0,0,0)
#define CVTPK(a,b) __builtin_amdgcn_cvt_pkrtz(a,b)

#if __has_builtin(__builtin_amdgcn_exp2f)
#define EXP2(x) __builtin_amdgcn_exp2f(x)
#else
#define EXP2(x) exp2f(x)
#endif

static __device__ __forceinline__ float dot2acc(h16x2 a, float c) {
#if __has_builtin(__builtin_amdgcn_fdot2)
    const h16x2 one = { (__fp16)1.f, (__fp16)1.f };
    return __builtin_amdgcn_fdot2(a, one, c, false);
#else
    return c + (float)a[0] + (float)a[1];
#endif
}

typedef __attribute__((address_space(1))) void gvoid_t;
typedef __attribute__((address_space(3))) void svoid_t;
#define AS1(p) ((gvoid_t*)(uintptr_t)(p))
#define AS3(p) ((svoid_t*)(uint32_t)(uintptr_t)(p))

static constexpr int Bc = 2, Tc = 2048, Dc = 768, Hc = 12;
static constexpr int Mc = Bc * Tc;                      // 4096
static constexpr float SC2 = 0.18033688011112042f;      // (1/8) * log2(e), folded into Wq/bq

union PA { f16x8 v; h16x2 h[4]; };

// Swizzled LDS frag read for 32x32 MFMA A/B operands.
// Tile = 64 rows x 8 chunks of 16B, storage chunk = logical ^ (row&7).
// row = ROWOFF + (lane&31); CHUNK already includes hi where needed.
#define FRAG32(BASE, ROWOFF, CHUNK) \
    (*(const f16x8*)((const char*)(BASE) + \
        ((ROWOFF) + q32) * 128 + (((CHUNK) ^ g7) * 16)))

// ---------------- f32 -> f16 conversion (all inputs + weights; Wq pre-scaled) ----------------
__global__ __launch_bounds__(256) void conv_all(
    const float* __restrict__ q, const float* __restrict__ k, const float* __restrict__ v,
    const float* __restrict__ wq, const float* __restrict__ wk, const float* __restrict__ wv,
    const float* __restrict__ wo,
    f16* __restrict__ qh, f16* __restrict__ kh, f16* __restrict__ vh,
    f16* __restrict__ wqh, f16* __restrict__ wkh, f16* __restrict__ wvh, f16* __restrict__ woh)
{
    const int NI = (Mc * Dc) / 4;
    const int NW = (Dc * Dc) / 4;
    int i = blockIdx.x * 256 + threadIdx.x;
    if (i >= 3 * NI + 4 * NW) return;
    const float4* src; f16* dst; int j; float scl = 1.f;
    if (i < 3 * NI) {
        int a = i / NI; j = i - a * NI;
        src = (const float4*)(a == 0 ? q : (a == 1 ? k : v));
        dst = (a == 0 ? qh : (a == 1 ? kh : vh));
    } else {
        int t = i - 3 * NI;
        int a = t / NW; j = t - a * NW;
        src = (const float4*)(a == 0 ? wq : (a == 1 ? wk : (a == 2 ? wv : wo)));
        dst = (a == 0 ? wqh : (a == 1 ? wkh : (a == 2 ? wvh : woh)));
        if (a == 0) scl = SC2;
    }
    float4 f = src[j];
    f16x4v o = { (f16)(f.x * scl), (f16)(f.y * scl), (f16)(f.z * scl), (f16)(f.w * scl) };
    *(f16x4v*)(dst + 4 * j) = o;
}

// ---------------- 128x128 GEMM mainloop: C = A @ W^T over K=768 ----------------
__device__ __forceinline__ void gemm_tile_mainloop(
    const f16* __restrict__ A, const f16* __restrict__ W,
    int brow, int bcol, f16* As, f16* Bs, f32x4 acc[4][4])
{
    const int tid = threadIdx.x;
    const int w = tid >> 6, lane = tid & 63;
    const int lg = lane & 15, hg = lane >> 4;
    const int wr = w >> 1, wc = w & 1;

    for (int kt = 0; kt < 768 / 32; ++kt) {
        const int k0 = kt * 32;
#pragma unroll
        for (int j = 0; j < 2; ++j) {
            int p = (w * 2 + j) * 1024 + lane * 16;
            int r = p >> 6;
            int ke = (p & 63) >> 1;
            __builtin_amdgcn_global_load_lds(AS1(A + (size_t)(brow + r) * 768 + k0 + ke),
                                             AS3((char*)As + (w * 2 + j) * 1024), 16, 0, 0);
            __builtin_amdgcn_global_load_lds(AS1(W + (size_t)(bcol + r) * 768 + k0 + ke),
                                             AS3((char*)Bs + (w * 2 + j) * 1024), 16, 0, 0);
        }
        __syncthreads();
        f16x8 af[4], bf[4];
#pragma unroll
        for (int m = 0; m < 4; ++m)
            af[m] = *(const f16x8*)(As + (wr * 64 + m * 16 + lg) * 32 + hg * 8);
#pragma unroll
        for (int n = 0; n < 4; ++n)
            bf[n] = *(const f16x8*)(Bs + (wc * 64 + n * 16 + lg) * 32 + hg * 8);
#pragma unroll
        for (int m = 0; m < 4; ++m)
#pragma unroll
            for (int n = 0; n < 4; ++n)
                acc[m][n] = MFMA16(af[m], bf[n], acc[m][n]);
        __syncthreads();
    }
}

// ---------------- QKV projections (z: 0=Q-scaled, 1=K, 2=V-transposed+sigma-permuted) ----------------
__global__ __launch_bounds__(256) void qkv_proj(
    const f16* __restrict__ qh, const f16* __restrict__ kh, const f16* __restrict__ vh,
    const f16* __restrict__ wqh, const f16* __restrict__ wkh, const f16* __restrict__ wvh,
    const float* __restrict__ bq, const float* __restrict__ bk, const float* __restrict__ bv,
    f16* __restrict__ Qp, f16* __restrict__ Kp, f16* __restrict__ Vt)
{
    __shared__ f16 As[128 * 32], Bs[128 * 32];
    const int z = blockIdx.z;
    const f16* A = (z == 0) ? qh : (z == 1) ? kh : vh;
    const f16* W = (z == 0) ? wqh : (z == 1) ? wkh : wvh;
    const float* bias = (z == 0) ? bq : (z == 1) ? bk : bv;
    const int brow = blockIdx.y * 128, bcol = blockIdx.x * 128;

    f32x4 acc[4][4];
    const f32x4 z4 = { 0.f, 0.f, 0.f, 0.f };
#pragma unroll
    for (int m = 0; m < 4; ++m)
#pragma unroll
        for (int n = 0; n < 4; ++n) acc[m][n] = z4;

    gemm_tile_mainloop(A, W, brow, bcol, As, Bs, acc);

    const int tid = threadIdx.x, w = tid >> 6, lane = tid & 63;
    const int lg = lane & 15, hg = lane >> 4, wr = w >> 1, wc = w & 1;
#pragma unroll
    for (int n = 0; n < 4; ++n) {
        const int c = bcol + wc * 64 + n * 16 + lg;
        const float bval = (z == 0) ? bias[c] * SC2 : bias[c];
#pragma unroll
        for (int m = 0; m < 4; ++m) {
            const int r0 = brow + wr * 64 + m * 16 + hg * 4;
#pragma unroll
            for (int r = 0; r < 4; ++r) {
                const float val = acc[m][n][r] + bval;
                const int row = r0 + r;
                if (z == 0) {
                    Qp[(size_t)row * 768 + c] = (f16)val;
                } else if (z == 1) {
                    Kp[(size_t)row * 768 + c] = (f16)val;
                } else {
                    const int bb = row >> 11, t = row & 2047;
                    const int hh = c >> 6, d = c & 63;
                    // sigma involution within 32-block: swap k 4-7 <-> 8-11 (mod 16)
                    const int tl = t & 31;
                    const int sw = ((tl >> 2) ^ (tl >> 3)) & 1;
                    const int tp = (t & ~31) | (tl ^ (sw * 12));
                    Vt[(((size_t)(bb * 12 + hh)) * 64 + d) * 2048 + tp] = (f16)val;
                }
            }
        }
    }
}

// ---------------- output projection ----------------
__global__ __launch_bounds__(256) void out_proj(
    const f16* __restrict__ ctx, const f16* __restrict__ woh,
    const float* __restrict__ bo, float* __restrict__ out)
{
    __shared__ f16 As[128 * 32], Bs[128 * 32];
    const int brow = blockIdx.y * 128, bcol = blockIdx.x * 128;
    f32x4 acc[4][4];
    const f32x4 z4 = { 0.f, 0.f, 0.f, 0.f };
#pragma unroll
    for (int m = 0; m < 4; ++m)
#pragma unroll
        for (int n = 0; n < 4; ++n) acc[m][n] = z4;

    gemm_tile_mainloop(ctx, woh, brow, bcol, As, Bs, acc);

    const int tid = threadIdx.x, w = tid >> 6, lane = tid & 63;
    const int lg = lane & 15, hg = lane >> 4, wr = w >> 1, wc = w & 1;
#pragma unroll
    for (int n = 0; n < 4; ++n) {
        const int c = bcol + wc * 64 + n * 16 + lg;
        const float bval = bo[c];
#pragma unroll
        for (int m = 0; m < 4; ++m) {
            const int r0 = brow + wr * 64 + m * 16 + hg * 4;
#pragma unroll
            for (int r = 0; r < 4; ++r)
                out[(size_t)(r0 + r) * 768 + c] = acc[m][n][r] + bval;
        }
    }
}

// ---------------- fused attention, 32x32x16 MFMA, 4 waves = (q-half, k-half) ----------------
__global__ __launch_bounds__(256, 3) void attn_out(
    const f16* __restrict__ Qp, const f16* __restrict__ Kp, const f16* __restrict__ Vt,
    float* __restrict__ l_inv, f16* __restrict__ ctx)
{
    __shared__ f16 Kbuf[2][4096];    // [64 k][8 chunks*8 f16], swizzled
    __shared__ f16 Vbuf[2][4096];    // [64 d][8 chunks*8 f16], swizzled (k sigma-permuted)
    __shared__ float Ored[2][32][64];  // [qh][q][d] partial O from kh=1 waves
    __shared__ float lred[2][2][32];   // [kh][qh][q]

    const int qt = blockIdx.x, h = blockIdx.y, b = blockIdx.z;
    const int tid = threadIdx.x, w = tid >> 6, lane = tid & 63;
    const int q32 = lane & 31, hi = lane >> 5, g7 = lane & 7;
    const int qh = w & 1, kh = w >> 1;
    const int wbase16 = (tid & ~63) * 16;

    const size_t qrow0 = (size_t)b * 2048 + qt * 64 + qh * 32;
    const int hcol = h * 64;

    // Q fragments (B operand): col=q32, kdim = hi*8+j  -> Q[q][dstep*16 + hi*8 + j]
    const f16* qb = Qp + (qrow0 + q32) * 768 + hcol + hi * 8;
    f16x8 bqf[4];
#pragma unroll
    for (int d = 0; d < 4; ++d) bqf[d] = *(const f16x8*)(qb + d * 16);

    const size_t kbase = (size_t)b * 2048;
    const f16* Vg = Vt + ((size_t)(b * 12 + h)) * 64 * 2048;

    f32x16 oacc[2];
#pragma unroll
    for (int dt = 0; dt < 2; ++dt)
#pragma unroll
        for (int r = 0; r < 16; ++r) oacc[dt][r] = 0.f;
    float lsum = 0.f;

#define STAGE_KV(KT_, BUF) do { \
    _Pragma("unroll") \
    for (int j_ = 0; j_ < 2; ++j_) { \
        const int p_ = j_ * 256 + tid; \
        const int row_ = p_ >> 3, c_ = (p_ & 7) ^ (row_ & 7); \
        __builtin_amdgcn_global_load_lds( \
            AS1(Kp + (kbase + (size_t)(KT_) * 64 + row_) * 768 + hcol + c_ * 8), \
            AS3((char*)&Kbuf[BUF][0] + j_ * 4096 + wbase16), 16, 0, 0); \
        __builtin_amdgcn_global_load_lds( \
            AS1(Vg + (size_t)row_ * 2048 + (KT_) * 64 + c_ * 8), \
            AS3((char*)&Vbuf[BUF][0] + j_ * 4096 + wbase16), 16, 0, 0); \
    } } while (0)

#define AOBODY(CUR) do { \
    const f16* Kb_ = &Kbuf[CUR][0]; const f16* Vb_ = &Vbuf[CUR][0]; \
    f32x16 sa; \
    _Pragma("unroll") \
    for (int r_ = 0; r_ < 16; ++r_) sa[r_] = 0.f; \
    sa = MFMA32(FRAG32(Kb_, kh * 32, 0 + hi), bqf[0], sa); \
    sa = MFMA32(FRAG32(Kb_, kh * 32, 2 + hi), bqf[1], sa); \
    sa = MFMA32(FRAG32(Kb_, kh * 32, 4 + hi), bqf[2], sa); \
    sa = MFMA32(FRAG32(Kb_, kh * 32, 6 + hi), bqf[3], sa); \
    float p[16]; \
    _Pragma("unroll") \
    for (int r_ = 0; r_ < 16; ++r_) p[r_] = EXP2(sa[r_]); \
    PA pa0, pa1; \
    pa0.h[0] = CVTPK(p[0], p[1]);   pa0.h[1] = CVTPK(p[2], p[3]); \
    pa0.h[2] = CVTPK(p[4], p[5]);   pa0.h[3] = CVTPK(p[6], p[7]); \
    pa1.h[0] = CVTPK(p[8], p[9]);   pa1.h[1] = CVTPK(p[10], p[11]); \
    pa1.h[2] = CVTPK(p[12], p[13]); pa1.h[3] = CVTPK(p[14], p[15]); \
    float t0_ = 0.f, t1_ = 0.f; \
    t0_ = dot2acc(pa0.h[0], t0_); t0_ = dot2acc(pa0.h[1], t0_); \
    t0_ = dot2acc(pa0.h[2], t0_); t0_ = dot2acc(pa0.h[3], t0_); \
    t1_ = dot2acc(pa1.h[0], t1_); t1_ = dot2acc(pa1.h[1], t1_); \
    t1_ = dot2acc(pa1.h[2], t1_); t1_ = dot2acc(pa1.h[3], t1_); \
    lsum += t0_ + t1_; \
    oacc[0] = MFMA32(FRAG32(Vb_, 0,  kh * 4 + 0 + hi), pa0.v, oacc[0]); \
    oacc[0] = MFMA32(FRAG32(Vb_, 0,  kh * 4 + 2 + hi), pa1.v, oacc[0]); \
    oacc[1] = MFMA32(FRAG32(Vb_, 32, kh * 4 + 0 + hi), pa0.v, oacc[1]); \
    oacc[1] = MFMA32(FRAG32(Vb_, 32, kh * 4 + 2 + hi), pa1.v, oacc[1]); \
} while (0)

    STAGE_KV(0, 0);
    __syncthreads();
    for (int kt = 0; kt < 32; ++kt) {
        const int cur = kt & 1;
        if (kt < 31) STAGE_KV(kt + 1, cur ^ 1);
        AOBODY(cur);
        __syncthreads();
    }
#undef STAGE_KV
#undef AOBODY

    // ---- cross-wave reduction: combine k-halves ----
    lsum += __shfl_xor(lsum, 32);
    if (hi == 0) lred[kh][qh][q32] = lsum;
    if (kh == 1) {
#pragma unroll
        for (int dt = 0; dt < 2; ++dt)
#pragma unroll
            for (int g = 0; g < 4; ++g) {
                float4 v4 = { oacc[dt][g * 4 + 0], oacc[dt][g * 4 + 1],
                              oacc[dt][g * 4 + 2], oacc[dt][g * 4 + 3] };
                *(float4*)&Ored[qh][q32][dt * 32 + g * 8 + hi * 4] = v4;
            }
    }
    __syncthreads();
    if (kh == 0) {
        const float iv = 1.f / (lred[0][qh][q32] + lred[1][qh][q32]);
        if (hi == 0)
            l_inv[((size_t)(b * 12 + h)) * 2048 + qt * 64 + qh * 32 + q32] = iv;
        f16* cb = ctx + (qrow0 + q32) * 768 + hcol;
#pragma unroll
        for (int dt = 0; dt < 2; ++dt)
#pragma unroll
            for (int g = 0; g < 4; ++g) {
                const int d0 = dt * 32 + g * 8 + hi * 4;
                const float4 o4 = *(const float4*)&Ored[qh][q32][d0];
                f16x4v s;
#pragma unroll
                for (int e = 0; e < 4; ++e)
                    s[e] = (f16)((oacc[dt][g * 4 + e] + (&o4.x)[e]) * iv);
                *(f16x4v*)(cb + d0) = s;
            }
    }
}

// ---------------- attn mean over heads, 32x32x16 MFMA, 2 waves = q-halves ----------------
__global__ __launch_bounds__(128, 2) void attn_mean(
    const f16* __restrict__ Qp, const f16* __restrict__ Kp,
    const float* __restrict__ l_inv, float* __restrict__ om)
{
    __shared__ f16 Qbuf[2][4096];   // [64 q][8 chunks], swizzled
    __shared__ f16 Kbuf[2][4096];   // [64 k][8 chunks], swizzled

    const int kt = blockIdx.x, qt = blockIdx.y, b = blockIdx.z;
    const int tid = threadIdx.x, lane = tid & 63;
    const int q32 = lane & 31, hi = lane >> 5, g7 = lane & 7;
    const int qh = tid >> 6;
    const int wb = (tid & 64) * 16;   // wave-uniform LDS byte base component

    const size_t qtrow = (size_t)b * 2048 + qt * 64;
    const size_t ktrow = (size_t)b * 2048 + kt * 64;

    f32x16 macc[2];
#pragma unroll
    for (int kk = 0; kk < 2; ++kk)
#pragma unroll
        for (int r = 0; r < 16; ++r) macc[kk][r] = 0.f;

#define STAGE_QK(H_, BUF) do { \
    _Pragma("unroll") \
    for (int j_ = 0; j_ < 4; ++j_) { \
        const int p_ = j_ * 128 + tid; \
        const int row_ = p_ >> 3, c_ = (p_ & 7) ^ (row_ & 7); \
        __builtin_amdgcn_global_load_lds( \
            AS1(Qp + (qtrow + row_) * 768 + (H_) * 64 + c_ * 8), \
            AS3((char*)&Qbuf[BUF][0] + j_ * 2048 + wb), 16, 0, 0); \
        __builtin_amdgcn_global_load_lds( \
            AS1(Kp + (ktrow + row_) * 768 + (H_) * 64 + c_ * 8), \
            AS3((char*)&Kbuf[BUF][0] + j_ * 2048 + wb), 16, 0, 0); \
    } } while (0)

#define MBODY(H_, CUR) do { \
    const f16* Qb_ = &Qbuf[CUR][0]; const f16* Kb_ = &Kbuf[CUR][0]; \
    f16x8 qf[4]; \
    _Pragma("unroll") \
    for (int d_ = 0; d_ < 4; ++d_) qf[d_] = FRAG32(Qb_, qh * 32, d_ * 2 + hi); \
    f32x16 sa0, sa1; \
    _Pragma("unroll") \
    for (int r_ = 0; r_ < 16; ++r_) { sa0[r_] = 0.f; sa1[r_] = 0.f; } \
    sa0 = MFMA32(FRAG32(Kb_, 0,  0 + hi), qf[0], sa0); \
    sa0 = MFMA32(FRAG32(Kb_, 0,  2 + hi), qf[1], sa0); \
    sa0 = MFMA32(FRAG32(Kb_, 0,  4 + hi), qf[2], sa0); \
    sa0 = MFMA32(FRAG32(Kb_, 0,  6 + hi), qf[3], sa0); \
    sa1 = MFMA32(FRAG32(Kb_, 32, 0 + hi), qf[0], sa1); \
    sa1 = MFMA32(FRAG32(Kb_, 32, 2 + hi), qf[1], sa1); \
    sa1 = MFMA32(FRAG32(Kb_, 32, 4 + hi), qf[2], sa1); \
    sa1 = MFMA32(FRAG32(Kb_, 32, 6 + hi), qf[3], sa1); \
    const float ivv = l_inv[((size_t)(b * 12 + (H_))) * 2048 + qt * 64 + qh * 32 + q32]; \
    _Pragma("unroll") \
    for (int r_ = 0; r_ < 16; ++r_) { \
        macc[0][r_] += EXP2(sa0[r_]) * ivv; \
        macc[1][r_] += EXP2(sa1[r_]) * ivv; } \
} while (0)

    STAGE_QK(0, 0);
    __syncthreads();
    for (int h = 0; h < 12; ++h) {
        const int cur = h & 1;
        if (h < 11) STAGE_QK(h + 1, cur ^ 1);
        MBODY(h, cur);
        __syncthreads();
    }
#undef STAGE_QK
#undef MBODY

    float* ob = om + ((size_t)(b * 2048 + qt * 64 + qh * 32 + q32)) * 2048 + kt * 64;
#pragma unroll
    for (int kk = 0; kk < 2; ++kk)
#pragma unroll
        for (int g = 0; g < 4; ++g) {
            float4 v4 = { macc[kk][g * 4 + 0] * (1.0f / 12.0f),
                          macc[kk][g * 4 + 1] * (1.0f / 12.0f),
                          macc[kk][g * 4 + 2] * (1.0f / 12.0f),
                          macc[kk][g * 4 + 3] * (1.0f / 12.0f) };
            *(float4*)(ob + kk * 32 + g * 8 + hi * 4) = v4;
        }
}

// ---------------- launch ----------------
extern "C" void kernel_launch(void* const* d_in, const int* in_sizes, int n_in,
                              void* d_out, int out_size, void* d_ws, size_t ws_size,
                              hipStream_t stream) {
    const float* q  = (const float*)d_in[0];
    const float* k  = (const float*)d_in[1];
    const float* v  = (const float*)d_in[2];
    const float* Wq = (const float*)d_in[3];
    const float* bq = (const float*)d_in[4];
    const float* Wk = (const float*)d_in[5];
    const float* bk = (const float*)d_in[6];
    const float* Wv = (const float*)d_in[7];
    const float* bv = (const float*)d_in[8];
    const float* Wo = (const float*)d_in[9];
    const float* bo = (const float*)d_in[10];
    float* out = (float*)d_out;

    char* ws = (char*)d_ws;
    const size_t SZ_IN = (size_t)Mc * Dc * 2;
    const size_t SZ_W  = (size_t)Dc * Dc * 2;
    f16* qh  = (f16*)(ws);
    f16* kh  = (f16*)(ws + SZ_IN);
    f16* vh  = (f16*)(ws + 2 * SZ_IN);
    f16* wqh = (f16*)(ws + 3 * SZ_IN);
    f16* wkh = (f16*)(ws + 3 * SZ_IN + SZ_W);
    f16* wvh = (f16*)(ws + 3 * SZ_IN + 2 * SZ_W);
    f16* woh = (f16*)(ws + 3 * SZ_IN + 3 * SZ_W);
    f16* Qp  = (f16*)(ws + 3 * SZ_IN + 4 * SZ_W);
    f16* Kp  = (f16*)(ws + 4 * SZ_IN + 4 * SZ_W);
    f16* Vt  = (f16*)(ws + 5 * SZ_IN + 4 * SZ_W);
    f16* ctx = qh;                 // dead-buffer reuse
    float* l_inv = (float*)kh;     // dead-buffer reuse

    conv_all<<<dim3(11520), dim3(256), 0, stream>>>(q, k, v, Wq, Wk, Wv, Wo,
                                                    qh, kh, vh, wqh, wkh, wvh, woh);
    qkv_proj<<<dim3(6, 32, 3), dim3(256), 0, stream>>>(qh, kh, vh, wqh, wkh, wvh,
                                                       bq, bk, bv, Qp, Kp, Vt);
    attn_out<<<dim3(32, 12, 2), dim3(256), 0, stream>>>(Qp, Kp, Vt, l_inv, ctx);
    attn_mean<<<dim3(32, 32, 2), dim3(128), 0, stream>>>(Qp, Kp, l_inv,
                                                         out + (size_t)Mc * Dc);
    out_proj<<<dim3(6, 32, 1), dim3(256), 0, stream>>>(ctx, woh, bo, out);
}

// Round 7
// 131.175 us; speedup vs baseline: 3.6253x; 1.1071x over previous
//
#include <hip/hip_runtime.h>
#include <hip/hip_fp16.h>
#include <stdint.h>

typedef _Float16 f16;
typedef _Float16 f16x8 __attribute__((ext_vector_type(8)));
typedef _Float16 f16x4v __attribute__((ext_vector_type(4)));
typedef __fp16 h16x2 __attribute__((ext_vector_type(2)));   // cvt_pkrtz return type
typedef float f32x4 __attribute__((ext_vector_type(4)));
typedef float f32x16 __attribute__((ext_vector_type(16)));

#define MFMA16(a,b,c) __builtin_amdgcn_mfma_f32_16x16x32_f16(a,b,c,0,0,0)
#define MFMA32(a,b,c) __builtin_amdgcn_mfma_f32_32x32x16_f16(a,b,c,0,0,0)
#define CVTPK(a,b) __builtin_amdgcn_cvt_pkrtz(a,b)

#if __has_builtin(__builtin_amdgcn_exp2f)
#define EXP2(x) __builtin_amdgcn_exp2f(x)
#else
#define EXP2(x) exp2f(x)
#endif

static __device__ __forceinline__ float dot2acc(h16x2 a, float c) {
#if __has_builtin(__builtin_amdgcn_fdot2)
    const h16x2 one = { (__fp16)1.f, (__fp16)1.f };
    return __builtin_amdgcn_fdot2(a, one, c, false);
#else
    return c + (float)a[0] + (float)a[1];
#endif
}

typedef __attribute__((address_space(1))) void gvoid_t;
typedef __attribute__((address_space(3))) void svoid_t;
#define AS1(p) ((gvoid_t*)(uintptr_t)(p))
#define AS3(p) ((svoid_t*)(uint32_t)(uintptr_t)(p))

static constexpr int Bc = 2, Tc = 2048, Dc = 768, Hc = 12;
static constexpr int Mc = Bc * Tc;                      // 4096
static constexpr float SC2 = 0.18033688011112042f;      // (1/8) * log2(e), folded into Wq/bq

union PA { f16x8 v; h16x2 h[4]; };

// Swizzled LDS frag read for 32x32 MFMA A/B operands.
// Tile = 64 rows x 8 chunks of 16B, storage chunk = logical ^ (row&7).
#define FRAG32(BASE, ROWOFF, CHUNK) \
    (*(const f16x8*)((const char*)(BASE) + \
        ((ROWOFF) + q32) * 128 + (((CHUNK) ^ g7) * 16)))

// ---------------- f32 -> f16 conversion (all inputs + weights; Wq pre-scaled) ----------------
__global__ __launch_bounds__(256) void conv_all(
    const float* __restrict__ q, const float* __restrict__ k, const float* __restrict__ v,
    const float* __restrict__ wq, const float* __restrict__ wk, const float* __restrict__ wv,
    const float* __restrict__ wo,
    f16* __restrict__ qh, f16* __restrict__ kh, f16* __restrict__ vh,
    f16* __restrict__ wqh, f16* __restrict__ wkh, f16* __restrict__ wvh, f16* __restrict__ woh)
{
    const int NI = (Mc * Dc) / 4;
    const int NW = (Dc * Dc) / 4;
    int i = blockIdx.x * 256 + threadIdx.x;
    if (i >= 3 * NI + 4 * NW) return;
    const float4* src; f16* dst; int j; float scl = 1.f;
    if (i < 3 * NI) {
        int a = i / NI; j = i - a * NI;
        src = (const float4*)(a == 0 ? q : (a == 1 ? k : v));
        dst = (a == 0 ? qh : (a == 1 ? kh : vh));
    } else {
        int t = i - 3 * NI;
        int a = t / NW; j = t - a * NW;
        src = (const float4*)(a == 0 ? wq : (a == 1 ? wk : (a == 2 ? wv : wo)));
        dst = (a == 0 ? wqh : (a == 1 ? wkh : (a == 2 ? wvh : woh)));
        if (a == 0) scl = SC2;
    }
    float4 f = src[j];
    f16x4v o = { (f16)(f.x * scl), (f16)(f.y * scl), (f16)(f.z * scl), (f16)(f.w * scl) };
    *(f16x4v*)(dst + 4 * j) = o;
}

// ------- 128x128 GEMM mainloop, double-buffered prefetch: C = A @ W^T over K=768 -------
// As/Bs point to [2][4096] f16 buffers (8 KiB each half).
__device__ __forceinline__ void gemm_tile_mainloop_db(
    const f16* __restrict__ A, const f16* __restrict__ W,
    int brow, int bcol, f16* As, f16* Bs, f32x4 acc[4][4])
{
    const int tid = threadIdx.x;
    const int w = tid >> 6, lane = tid & 63;
    const int lg = lane & 15, hg = lane >> 4;
    const int wr = w >> 1, wc = w & 1;

#define GS(KT_, BUF_) do { \
    const int k0_ = (KT_) * 32; \
    _Pragma("unroll") \
    for (int j_ = 0; j_ < 2; ++j_) { \
        int p_ = (w * 2 + j_) * 1024 + lane * 16; \
        int r_ = p_ >> 6; \
        int ke_ = (p_ & 63) >> 1; \
        __builtin_amdgcn_global_load_lds(AS1(A + (size_t)(brow + r_) * 768 + k0_ + ke_), \
            AS3((char*)As + (BUF_) * 8192 + (w * 2 + j_) * 1024), 16, 0, 0); \
        __builtin_amdgcn_global_load_lds(AS1(W + (size_t)(bcol + r_) * 768 + k0_ + ke_), \
            AS3((char*)Bs + (BUF_) * 8192 + (w * 2 + j_) * 1024), 16, 0, 0); \
    } } while (0)

    GS(0, 0);
    __syncthreads();
    for (int kt = 0; kt < 24; ++kt) {
        const int cur = kt & 1;
        if (kt < 23) GS(kt + 1, cur ^ 1);
        const f16* As_ = As + cur * 4096;
        const f16* Bs_ = Bs + cur * 4096;
        f16x8 af[4], bf[4];
#pragma unroll
        for (int m = 0; m < 4; ++m)
            af[m] = *(const f16x8*)(As_ + (wr * 64 + m * 16 + lg) * 32 + hg * 8);
#pragma unroll
        for (int n = 0; n < 4; ++n)
            bf[n] = *(const f16x8*)(Bs_ + (wc * 64 + n * 16 + lg) * 32 + hg * 8);
#pragma unroll
        for (int m = 0; m < 4; ++m)
#pragma unroll
            for (int n = 0; n < 4; ++n)
                acc[m][n] = MFMA16(af[m], bf[n], acc[m][n]);
        __syncthreads();
    }
#undef GS
}

// ---------------- QKV projections (z: 0=Q-scaled, 1=K, 2=V-transposed+sigma-permuted) ----------------
__global__ __launch_bounds__(256) void qkv_proj(
    const f16* __restrict__ qh, const f16* __restrict__ kh, const f16* __restrict__ vh,
    const f16* __restrict__ wqh, const f16* __restrict__ wkh, const f16* __restrict__ wvh,
    const float* __restrict__ bq, const float* __restrict__ bk, const float* __restrict__ bv,
    f16* __restrict__ Qp, f16* __restrict__ Kp, f16* __restrict__ Vt)
{
    __shared__ f16 As[2][4096], Bs[2][4096];
    const int z = blockIdx.z;
    const f16* A = (z == 0) ? qh : (z == 1) ? kh : vh;
    const f16* W = (z == 0) ? wqh : (z == 1) ? wkh : wvh;
    const float* bias = (z == 0) ? bq : (z == 1) ? bk : bv;
    const int brow = blockIdx.y * 128, bcol = blockIdx.x * 128;

    f32x4 acc[4][4];
    const f32x4 z4 = { 0.f, 0.f, 0.f, 0.f };
#pragma unroll
    for (int m = 0; m < 4; ++m)
#pragma unroll
        for (int n = 0; n < 4; ++n) acc[m][n] = z4;

    gemm_tile_mainloop_db(A, W, brow, bcol, &As[0][0], &Bs[0][0], acc);

    const int tid = threadIdx.x, w = tid >> 6, lane = tid & 63;
    const int lg = lane & 15, hg = lane >> 4, wr = w >> 1, wc = w & 1;
#pragma unroll
    for (int n = 0; n < 4; ++n) {
        const int c = bcol + wc * 64 + n * 16 + lg;
        const float bval = (z == 0) ? bias[c] * SC2 : bias[c];
#pragma unroll
        for (int m = 0; m < 4; ++m) {
            const int r0 = brow + wr * 64 + m * 16 + hg * 4;
#pragma unroll
            for (int r = 0; r < 4; ++r) {
                const float val = acc[m][n][r] + bval;
                const int row = r0 + r;
                if (z == 0) {
                    Qp[(size_t)row * 768 + c] = (f16)val;
                } else if (z == 1) {
                    Kp[(size_t)row * 768 + c] = (f16)val;
                } else {
                    const int bb = row >> 11, t = row & 2047;
                    const int hh = c >> 6, d = c & 63;
                    // sigma involution within 32-block: swap k 4-7 <-> 8-11 (mod 16)
                    const int tl = t & 31;
                    const int sw = ((tl >> 2) ^ (tl >> 3)) & 1;
                    const int tp = (t & ~31) | (tl ^ (sw * 12));
                    Vt[(((size_t)(bb * 12 + hh)) * 64 + d) * 2048 + tp] = (f16)val;
                }
            }
        }
    }
}

// ---------------- fused attention, 32x32x16 MFMA, 4 waves = (q-half, k-half) ----------------
__global__ __launch_bounds__(256, 3) void attn_out(
    const f16* __restrict__ Qp, const f16* __restrict__ Kp, const f16* __restrict__ Vt,
    float* __restrict__ l_inv, f16* __restrict__ ctx)
{
    __shared__ f16 Kbuf[2][4096];    // [64 k][8 chunks*8 f16], swizzled
    __shared__ f16 Vbuf[2][4096];    // [64 d][8 chunks*8 f16], swizzled (k sigma-permuted)
    __shared__ float Ored[2][32][64];  // [qh][q][d] partial O from kh=1 waves
    __shared__ float lred[2][2][32];   // [kh][qh][q]

    const int qt = blockIdx.x, h = blockIdx.y, b = blockIdx.z;
    const int tid = threadIdx.x, w = tid >> 6, lane = tid & 63;
    const int q32 = lane & 31, hi = lane >> 5, g7 = lane & 7;
    const int qh = w & 1, kh = w >> 1;
    const int wbase16 = (tid & ~63) * 16;

    const size_t qrow0 = (size_t)b * 2048 + qt * 64 + qh * 32;
    const int hcol = h * 64;

    const f16* qb = Qp + (qrow0 + q32) * 768 + hcol + hi * 8;
    f16x8 bqf[4];
#pragma unroll
    for (int d = 0; d < 4; ++d) bqf[d] = *(const f16x8*)(qb + d * 16);

    const size_t kbase = (size_t)b * 2048;
    const f16* Vg = Vt + ((size_t)(b * 12 + h)) * 64 * 2048;

    f32x16 oacc[2];
#pragma unroll
    for (int dt = 0; dt < 2; ++dt)
#pragma unroll
        for (int r = 0; r < 16; ++r) oacc[dt][r] = 0.f;
    float lsum = 0.f;

#define STAGE_KV(KT_, BUF) do { \
    _Pragma("unroll") \
    for (int j_ = 0; j_ < 2; ++j_) { \
        const int p_ = j_ * 256 + tid; \
        const int row_ = p_ >> 3, c_ = (p_ & 7) ^ (row_ & 7); \
        __builtin_amdgcn_global_load_lds( \
            AS1(Kp + (kbase + (size_t)(KT_) * 64 + row_) * 768 + hcol + c_ * 8), \
            AS3((char*)&Kbuf[BUF][0] + j_ * 4096 + wbase16), 16, 0, 0); \
        __builtin_amdgcn_global_load_lds( \
            AS1(Vg + (size_t)row_ * 2048 + (KT_) * 64 + c_ * 8), \
            AS3((char*)&Vbuf[BUF][0] + j_ * 4096 + wbase16), 16, 0, 0); \
    } } while (0)

#define AOBODY(CUR) do { \
    const f16* Kb_ = &Kbuf[CUR][0]; const f16* Vb_ = &Vbuf[CUR][0]; \
    f32x16 sa; \
    _Pragma("unroll") \
    for (int r_ = 0; r_ < 16; ++r_) sa[r_] = 0.f; \
    sa = MFMA32(FRAG32(Kb_, kh * 32, 0 + hi), bqf[0], sa); \
    sa = MFMA32(FRAG32(Kb_, kh * 32, 2 + hi), bqf[1], sa); \
    sa = MFMA32(FRAG32(Kb_, kh * 32, 4 + hi), bqf[2], sa); \
    sa = MFMA32(FRAG32(Kb_, kh * 32, 6 + hi), bqf[3], sa); \
    float p[16]; \
    _Pragma("unroll") \
    for (int r_ = 0; r_ < 16; ++r_) p[r_] = EXP2(sa[r_]); \
    PA pa0, pa1; \
    pa0.h[0] = CVTPK(p[0], p[1]);   pa0.h[1] = CVTPK(p[2], p[3]); \
    pa0.h[2] = CVTPK(p[4], p[5]);   pa0.h[3] = CVTPK(p[6], p[7]); \
    pa1.h[0] = CVTPK(p[8], p[9]);   pa1.h[1] = CVTPK(p[10], p[11]); \
    pa1.h[2] = CVTPK(p[12], p[13]); pa1.h[3] = CVTPK(p[14], p[15]); \
    float t0_ = 0.f, t1_ = 0.f; \
    t0_ = dot2acc(pa0.h[0], t0_); t0_ = dot2acc(pa0.h[1], t0_); \
    t0_ = dot2acc(pa0.h[2], t0_); t0_ = dot2acc(pa0.h[3], t0_); \
    t1_ = dot2acc(pa1.h[0], t1_); t1_ = dot2acc(pa1.h[1], t1_); \
    t1_ = dot2acc(pa1.h[2], t1_); t1_ = dot2acc(pa1.h[3], t1_); \
    lsum += t0_ + t1_; \
    oacc[0] = MFMA32(FRAG32(Vb_, 0,  kh * 4 + 0 + hi), pa0.v, oacc[0]); \
    oacc[0] = MFMA32(FRAG32(Vb_, 0,  kh * 4 + 2 + hi), pa1.v, oacc[0]); \
    oacc[1] = MFMA32(FRAG32(Vb_, 32, kh * 4 + 0 + hi), pa0.v, oacc[1]); \
    oacc[1] = MFMA32(FRAG32(Vb_, 32, kh * 4 + 2 + hi), pa1.v, oacc[1]); \
} while (0)

    STAGE_KV(0, 0);
    __syncthreads();
    for (int kt = 0; kt < 32; ++kt) {
        const int cur = kt & 1;
        if (kt < 31) STAGE_KV(kt + 1, cur ^ 1);
        AOBODY(cur);
        __syncthreads();
    }
#undef STAGE_KV
#undef AOBODY

    // ---- cross-wave reduction: combine k-halves ----
    lsum += __shfl_xor(lsum, 32);
    if (hi == 0) lred[kh][qh][q32] = lsum;
    if (kh == 1) {
#pragma unroll
        for (int dt = 0; dt < 2; ++dt)
#pragma unroll
            for (int g = 0; g < 4; ++g) {
                float4 v4 = { oacc[dt][g * 4 + 0], oacc[dt][g * 4 + 1],
                              oacc[dt][g * 4 + 2], oacc[dt][g * 4 + 3] };
                *(float4*)&Ored[qh][q32][dt * 32 + g * 8 + hi * 4] = v4;
            }
    }
    __syncthreads();
    if (kh == 0) {
        const float iv = 1.f / (lred[0][qh][q32] + lred[1][qh][q32]);
        if (hi == 0)
            l_inv[((size_t)(b * 12 + h)) * 2048 + qt * 64 + qh * 32 + q32] = iv;
        f16* cb = ctx + (qrow0 + q32) * 768 + hcol;
#pragma unroll
        for (int dt = 0; dt < 2; ++dt)
#pragma unroll
            for (int g = 0; g < 4; ++g) {
                const int d0 = dt * 32 + g * 8 + hi * 4;
                const float4 o4 = *(const float4*)&Ored[qh][q32][d0];
                f16x4v s;
#pragma unroll
                for (int e = 0; e < 4; ++e)
                    s[e] = (f16)((oacc[dt][g * 4 + e] + (&o4.x)[e]) * iv);
                *(f16x4v*)(cb + d0) = s;
            }
    }
}

// ------- fused tail: blocks [0,192) = out_proj, [192,2240) = attn_mean (4-wave) -------
__global__ __launch_bounds__(256) void tail_fused(
    const f16* __restrict__ ctx, const f16* __restrict__ woh,
    const float* __restrict__ bo, float* __restrict__ out,
    const f16* __restrict__ Qp, const f16* __restrict__ Kp,
    const float* __restrict__ l_inv, float* __restrict__ om)
{
    __shared__ f16 sh[4][4096];   // 32 KiB, shared by both bodies

    const int tid = threadIdx.x, w = tid >> 6, lane = tid & 63;

    if (blockIdx.x < 192) {
        // ================= out_proj =================
        const int brow = (blockIdx.x / 6) * 128, bcol = (blockIdx.x % 6) * 128;
        f32x4 acc[4][4];
        const f32x4 z4 = { 0.f, 0.f, 0.f, 0.f };
#pragma unroll
        for (int m = 0; m < 4; ++m)
#pragma unroll
            for (int n = 0; n < 4; ++n) acc[m][n] = z4;

        gemm_tile_mainloop_db(ctx, woh, brow, bcol, &sh[0][0], &sh[2][0], acc);

        const int lg = lane & 15, hg = lane >> 4, wr = w >> 1, wc = w & 1;
#pragma unroll
        for (int n = 0; n < 4; ++n) {
            const int c = bcol + wc * 64 + n * 16 + lg;
            const float bval = bo[c];
#pragma unroll
            for (int m = 0; m < 4; ++m) {
                const int r0 = brow + wr * 64 + m * 16 + hg * 4;
#pragma unroll
                for (int r = 0; r < 4; ++r)
                    out[(size_t)(r0 + r) * 768 + c] = acc[m][n][r] + bval;
            }
        }
    } else {
        // ================= attn_mean, 4 waves = (q-half, k-half) quadrants =================
        const int mb = blockIdx.x - 192;              // [0, 2048)
        const int kt = mb & 31, r2 = mb >> 5;
        const int qt = r2 & 31, b = r2 >> 5;
        const int q32 = lane & 31, hi = lane >> 5, g7 = lane & 7;
        const int qh = w & 1, kh = w >> 1;
        const int wbase16 = (tid & ~63) * 16;

        const size_t qtrow = (size_t)b * 2048 + qt * 64;
        const size_t ktrow = (size_t)b * 2048 + kt * 64;

        f32x16 macc;
#pragma unroll
        for (int r = 0; r < 16; ++r) macc[r] = 0.f;

#define MSTAGE(H_, BUF) do { \
    _Pragma("unroll") \
    for (int j_ = 0; j_ < 2; ++j_) { \
        const int p_ = j_ * 256 + tid; \
        const int row_ = p_ >> 3, c_ = (p_ & 7) ^ (row_ & 7); \
        __builtin_amdgcn_global_load_lds( \
            AS1(Qp + (qtrow + row_) * 768 + (H_) * 64 + c_ * 8), \
            AS3((char*)&sh[0][0] + (BUF) * 8192 + j_ * 4096 + wbase16), 16, 0, 0); \
        __builtin_amdgcn_global_load_lds( \
            AS1(Kp + (ktrow + row_) * 768 + (H_) * 64 + c_ * 8), \
            AS3((char*)&sh[2][0] + (BUF) * 8192 + j_ * 4096 + wbase16), 16, 0, 0); \
    } } while (0)

#define MBODY(H_, CUR) do { \
    const f16* Qb_ = (const f16*)((const char*)&sh[0][0] + (CUR) * 8192); \
    const f16* Kb_ = (const f16*)((const char*)&sh[2][0] + (CUR) * 8192); \
    f16x8 qf[4]; \
    _Pragma("unroll") \
    for (int d_ = 0; d_ < 4; ++d_) qf[d_] = FRAG32(Qb_, qh * 32, d_ * 2 + hi); \
    f32x16 sa; \
    _Pragma("unroll") \
    for (int r_ = 0; r_ < 16; ++r_) sa[r_] = 0.f; \
    sa = MFMA32(FRAG32(Kb_, kh * 32, 0 + hi), qf[0], sa); \
    sa = MFMA32(FRAG32(Kb_, kh * 32, 2 + hi), qf[1], sa); \
    sa = MFMA32(FRAG32(Kb_, kh * 32, 4 + hi), qf[2], sa); \
    sa = MFMA32(FRAG32(Kb_, kh * 32, 6 + hi), qf[3], sa); \
    const float ivv = l_inv[((size_t)(b * 12 + (H_))) * 2048 + qt * 64 + qh * 32 + q32]; \
    _Pragma("unroll") \
    for (int r_ = 0; r_ < 16; ++r_) macc[r_] += EXP2(sa[r_]) * ivv; \
} while (0)

        MSTAGE(0, 0);
        __syncthreads();
        for (int h = 0; h < 12; ++h) {
            const int cur = h & 1;
            if (h < 11) MSTAGE(h + 1, cur ^ 1);
            MBODY(h, cur);
            __syncthreads();
        }
#undef MSTAGE
#undef MBODY

        float* ob = om + ((size_t)(b * 2048 + qt * 64 + qh * 32 + q32)) * 2048
                  + kt * 64 + kh * 32;
#pragma unroll
        for (int g = 0; g < 4; ++g) {
            float4 v4 = { macc[g * 4 + 0] * (1.0f / 12.0f),
                          macc[g * 4 + 1] * (1.0f / 12.0f),
                          macc[g * 4 + 2] * (1.0f / 12.0f),
                          macc[g * 4 + 3] * (1.0f / 12.0f) };
            *(float4*)(ob + g * 8 + hi * 4) = v4;
        }
    }
}

// ---------------- launch ----------------
extern "C" void kernel_launch(void* const* d_in, const int* in_sizes, int n_in,
                              void* d_out, int out_size, void* d_ws, size_t ws_size,
                              hipStream_t stream) {
    const float* q  = (const float*)d_in[0];
    const float* k  = (const float*)d_in[1];
    const float* v  = (const float*)d_in[2];
    const float* Wq = (const float*)d_in[3];
    const float* bq = (const float*)d_in[4];
    const float* Wk = (const float*)d_in[5];
    const float* bk = (const float*)d_in[6];
    const float* Wv = (const float*)d_in[7];
    const float* bv = (const float*)d_in[8];
    const float* Wo = (const float*)d_in[9];
    const float* bo = (const float*)d_in[10];
    float* out = (float*)d_out;

    char* ws = (char*)d_ws;
    const size_t SZ_IN = (size_t)Mc * Dc * 2;
    const size_t SZ_W  = (size_t)Dc * Dc * 2;
    f16* qh  = (f16*)(ws);
    f16* kh  = (f16*)(ws + SZ_IN);
    f16* vh  = (f16*)(ws + 2 * SZ_IN);
    f16* wqh = (f16*)(ws + 3 * SZ_IN);
    f16* wkh = (f16*)(ws + 3 * SZ_IN + SZ_W);
    f16* wvh = (f16*)(ws + 3 * SZ_IN + 2 * SZ_W);
    f16* woh = (f16*)(ws + 3 * SZ_IN + 3 * SZ_W);
    f16* Qp  = (f16*)(ws + 3 * SZ_IN + 4 * SZ_W);
    f16* Kp  = (f16*)(ws + 4 * SZ_IN + 4 * SZ_W);
    f16* Vt  = (f16*)(ws + 5 * SZ_IN + 4 * SZ_W);
    f16* ctx = qh;                 // dead-buffer reuse
    float* l_inv = (float*)kh;     // dead-buffer reuse

    conv_all<<<dim3(11520), dim3(256), 0, stream>>>(q, k, v, Wq, Wk, Wv, Wo,
                                                    qh, kh, vh, wqh, wkh, wvh, woh);
    qkv_proj<<<dim3(6, 32, 3), dim3(256), 0, stream>>>(qh, kh, vh, wqh, wkh, wvh,
                                                       bq, bk, bv, Qp, Kp, Vt);
    attn_out<<<dim3(32, 12, 2), dim3(256), 0, stream>>>(Qp, Kp, Vt, l_inv, ctx);
    tail_fused<<<dim3(2240), dim3(256), 0, stream>>>(ctx, woh, bo, out,
                                                     Qp, Kp, l_inv,
                                                     out + (size_t)Mc * Dc);
}